// Round 1
// baseline (2311.767 us; speedup 1.0000x reference)
//
#include <hip/hip_runtime.h>
#include <hip/hip_bf16.h>

#define NWAVES_PER_BLOCK 4

// ---------------------------------------------------------------------------
// Encode: h_s = relu(redshift * enc_s_w^T + b), h_v = shapes @ enc_v_w^T
// Node layout: node[n*64 + 0..31] = h_s, node[n*64 + 32..63] = h_v
// ---------------------------------------------------------------------------
__global__ void encode_kernel(const float* __restrict__ redshift,
                              const float* __restrict__ shapes,
                              const float* __restrict__ enc_s_w,
                              const float* __restrict__ enc_s_b,
                              const float* __restrict__ enc_v_w,
                              float* __restrict__ node, int N_) {
  int tid = blockIdx.x * blockDim.x + threadIdx.x;
  int n = tid >> 5;
  int j = tid & 31;
  if (n >= N_) return;
  float r = redshift[n];
  float hs = fmaxf(fmaf(r, enc_s_w[j], enc_s_b[j]), 0.0f);
  float x0 = shapes[n * 2 + 0];
  float x1 = shapes[n * 2 + 1];
  float hv = fmaf(x0, enc_v_w[j * 2 + 0], x1 * enc_v_w[j * 2 + 1]);
  node[(size_t)n * 64 + j] = hs;
  node[(size_t)n * 64 + 32 + j] = hv;
}

// ---------------------------------------------------------------------------
// Per-edge geometry (layer-invariant since orientation == 0 always):
// geo = [dist, cos(2*phi), sin(2*phi), 0]; also narrow indices to int32.
// ---------------------------------------------------------------------------
__global__ void geo_kernel(const int* __restrict__ ei,
                           const float* __restrict__ pos,
                           int* __restrict__ srcA, int* __restrict__ dstA,
                           float4* __restrict__ geo4, int E_) {
  int e = blockIdx.x * blockDim.x + threadIdx.x;
  if (e >= E_) return;
  int s = ei[e];
  int d = ei[E_ + e];
  srcA[e] = s;
  dstA[e] = d;
  float dx = pos[s * 2 + 0] - pos[d * 2 + 0];
  float dy = pos[s * 2 + 1] - pos[d * 2 + 1];
  float r2 = fmaf(dx, dx, dy * dy);
  float dist = sqrtf(r2) + 1e-6f;
  float c2 = 1.0f, s2 = 0.0f;
  if (r2 > 0.0f) {
    float inv = 1.0f / r2;
    c2 = (dx * dx - dy * dy) * inv;
    s2 = 2.0f * dx * dy * inv;
  }
  geo4[e] = make_float4(dist, c2, s2, 0.0f);
}

// ---------------------------------------------------------------------------
// Simple float4 copy (init accumulation buffer = current h)
// ---------------------------------------------------------------------------
__global__ void copy_kernel(const float4* __restrict__ a, float4* __restrict__ b, int n4) {
  int i = blockIdx.x * blockDim.x + threadIdx.x;
  if (i < n4) b[i] = a[i];
}

// ---------------------------------------------------------------------------
// Message + scatter-add. One wave per edge (grid-stride).
// Lane j owns output feature j: holds W1 row j (zero-padded to 100) and
// W2 row j in registers. msg_in (99 floats) staged in per-wave LDS,
// consumed via broadcast b128 reads. hid round-trips through LDS.
// ---------------------------------------------------------------------------
__global__ __launch_bounds__(256, 2) void msg_kernel(
    const float* __restrict__ nodeIn, float* __restrict__ nodeOut,
    const int* __restrict__ srcA, const int* __restrict__ dstA,
    const float4* __restrict__ geo4,
    const float* __restrict__ W1, const float* __restrict__ b1,
    const float* __restrict__ W2, const float* __restrict__ b2, int E_) {
  __shared__ __align__(16) float lds[NWAVES_PER_BLOCK][104 + 64];
  const int lane = threadIdx.x & 63;
  const int wib = threadIdx.x >> 6;
  const int wave = blockIdx.x * NWAVES_PER_BLOCK + wib;
  const int nWaves = gridDim.x * NWAVES_PER_BLOCK;

  // Per-lane weight rows (held in registers; all accesses compile-time idx).
  float w1[100];
#pragma unroll
  for (int k = 0; k < 99; ++k) w1[k] = W1[lane * 99 + k];
  w1[99] = 0.0f;
  float w2[64];
#pragma unroll
  for (int k = 0; k < 64; ++k) w2[k] = W2[lane * 64 + k];
  const float bb1 = b1[lane];
  const float bb2 = b2[lane];

  float* msg = lds[wib];
  float* hidb = lds[wib] + 104;

  for (int e = wave; e < E_; e += nWaves) {
    int s = srcA[e];
    int d = dstA[e];
    // Stage msg_in = [h_s[src](32) | h_s[dst](32) | h_v[src](32) | geo(3),0]
    if (lane < 25) {
      float4 v;
      if (lane < 24) {
        int base;
        if (lane < 8)       base = s * 64 + lane * 4;
        else if (lane < 16) base = d * 64 + (lane - 8) * 4;
        else                base = s * 64 + 32 + (lane - 16) * 4;
        v = *reinterpret_cast<const float4*>(nodeIn + base);
      } else {
        v = geo4[e];
      }
      *reinterpret_cast<float4*>(msg + lane * 4) = v;
    }
    asm volatile("s_waitcnt lgkmcnt(0)" ::: "memory");

    // Layer A: hid_j = silu(b1_j + sum_k msg[k] * W1[j,k])
    float acc = bb1;
#pragma unroll
    for (int k4 = 0; k4 < 25; ++k4) {
      float4 m = reinterpret_cast<const float4*>(msg)[k4];
      acc = fmaf(m.x, w1[k4 * 4 + 0], acc);
      acc = fmaf(m.y, w1[k4 * 4 + 1], acc);
      acc = fmaf(m.z, w1[k4 * 4 + 2], acc);
      acc = fmaf(m.w, w1[k4 * 4 + 3], acc);
    }
    float hid = acc / (1.0f + __expf(-acc));

    hidb[lane] = hid;
    asm volatile("s_waitcnt lgkmcnt(0)" ::: "memory");

    // Layer B: raw_j = b2_j + sum_k hid[k] * W2[j,k]
    float acc2 = bb2;
#pragma unroll
    for (int k4 = 0; k4 < 16; ++k4) {
      float4 m = reinterpret_cast<const float4*>(hidb)[k4];
      acc2 = fmaf(m.x, w2[k4 * 4 + 0], acc2);
      acc2 = fmaf(m.y, w2[k4 * 4 + 1], acc2);
      acc2 = fmaf(m.z, w2[k4 * 4 + 2], acc2);
      acc2 = fmaf(m.w, w2[k4 * 4 + 3], acc2);
    }
    atomicAdd(nodeOut + (size_t)d * 64 + lane, acc2);
  }
}

// ---------------------------------------------------------------------------
// Final: de-interleave node buffer into d_out = [h_s (N*32) | h_v (N*32)]
// ---------------------------------------------------------------------------
__global__ void final_kernel(const float* __restrict__ node, float* __restrict__ out, int N_) {
  int tid = blockIdx.x * blockDim.x + threadIdx.x;
  int n = tid >> 5;
  int j = tid & 31;
  if (n >= N_) return;
  out[(size_t)n * 32 + j] = node[(size_t)n * 64 + j];
  out[(size_t)N_ * 32 + (size_t)n * 32 + j] = node[(size_t)n * 64 + 32 + j];
}

extern "C" void kernel_launch(void* const* d_in, const int* in_sizes, int n_in,
                              void* d_out, int out_size, void* d_ws, size_t ws_size,
                              hipStream_t stream) {
  const float* pos       = (const float*)d_in[0];
  const float* redshift  = (const float*)d_in[1];
  const float* shapes    = (const float*)d_in[2];
  const int*   ei        = (const int*)d_in[3];
  const float* enc_s_w   = (const float*)d_in[4];
  const float* enc_s_b   = (const float*)d_in[5];
  const float* enc_v_w   = (const float*)d_in[6];
  const float* W1        = (const float*)d_in[7];
  const float* b1        = (const float*)d_in[8];
  const float* W2        = (const float*)d_in[9];
  const float* b2        = (const float*)d_in[10];

  const int N_ = in_sizes[1];      // 50000
  const int E_ = in_sizes[3] / 2;  // 1000000

  // Workspace layout (all 16B-aligned given N_*64*4 and E_*4 are /16)
  char* ws = (char*)d_ws;
  float* nodeA = (float*)ws;                              // N*64 f32
  float* nodeB = nodeA + (size_t)N_ * 64;                 // N*64 f32
  int*   srcA  = (int*)(nodeB + (size_t)N_ * 64);         // E i32
  int*   dstA  = srcA + E_;                               // E i32
  float4* geo4 = (float4*)(dstA + E_);                    // E*4 f32

  encode_kernel<<<dim3((N_ * 32 + 255) / 256), dim3(256), 0, stream>>>(
      redshift, shapes, enc_s_w, enc_s_b, enc_v_w, nodeA, N_);
  geo_kernel<<<dim3((E_ + 255) / 256), dim3(256), 0, stream>>>(
      ei, pos, srcA, dstA, geo4, E_);

  float* cur = nodeA;
  float* nxt = nodeB;
  const int n4 = N_ * 16;  // N*64 floats / 4
  for (int l = 0; l < 3; ++l) {
    copy_kernel<<<dim3((n4 + 255) / 256), dim3(256), 0, stream>>>(
        (const float4*)cur, (float4*)nxt, n4);
    msg_kernel<<<dim3(1024), dim3(256), 0, stream>>>(
        cur, nxt, srcA, dstA, geo4,
        W1 + (size_t)l * 64 * 99, b1 + (size_t)l * 64,
        W2 + (size_t)l * 64 * 64, b2 + (size_t)l * 64, E_);
    float* t = cur; cur = nxt; nxt = t;
  }

  final_kernel<<<dim3((N_ * 32 + 255) / 256), dim3(256), 0, stream>>>(cur, (float*)d_out, N_);
}

// Round 2
// 704.320 us; speedup vs baseline: 3.2823x; 3.2823x over previous
//
#include <hip/hip_runtime.h>
#include <hip/hip_bf16.h>

#define WPB 4  // waves per block (256 threads)

__device__ __forceinline__ float silu_f(float x) { return x / (1.0f + __expf(-x)); }

// ---------------------------------------------------------------------------
// Encode: h_s = relu(redshift * enc_s_w^T + b), h_v = shapes @ enc_v_w^T
// Node layout: h[n*64 + 0..31] = h_s, h[n*64 + 32..63] = h_v
// ---------------------------------------------------------------------------
__global__ void encode_kernel(const float* __restrict__ redshift,
                              const float* __restrict__ shapes,
                              const float* __restrict__ enc_s_w,
                              const float* __restrict__ enc_s_b,
                              const float* __restrict__ enc_v_w,
                              float* __restrict__ h, int N_) {
  int tid = blockIdx.x * blockDim.x + threadIdx.x;
  int n = tid >> 5;
  int j = tid & 31;
  if (n >= N_) return;
  float r = redshift[n];
  float hs = fmaxf(fmaf(r, enc_s_w[j], enc_s_b[j]), 0.0f);
  float x0 = shapes[n * 2 + 0];
  float x1 = shapes[n * 2 + 1];
  float hv = fmaf(x0, enc_v_w[j * 2 + 0], x1 * enc_v_w[j * 2 + 1]);
  h[(size_t)n * 64 + j] = hs;
  h[(size_t)n * 64 + 32 + j] = hv;
}

__global__ void zero_kernel(int* __restrict__ p, int n) {
  int i = blockIdx.x * blockDim.x + threadIdx.x;
  if (i < n) p[i] = 0;
}

// ---------------------------------------------------------------------------
// CSR build (once): degree count, prefix scan, scatter src by dst.
// ---------------------------------------------------------------------------
__global__ void deg_kernel(const int* __restrict__ ei, int* __restrict__ deg, int E_) {
  int e = blockIdx.x * blockDim.x + threadIdx.x;
  if (e < E_) atomicAdd(&deg[ei[E_ + e]], 1);
}

// single block, 1024 threads; wave-scan + cross-wave + carry
__global__ void scan_kernel(const int* __restrict__ deg, int* __restrict__ rowptr, int n) {
  __shared__ int wsum[16];
  __shared__ int carry_s;
  int t = threadIdx.x, lane = t & 63, wid = t >> 6;
  if (t == 0) { carry_s = 0; rowptr[0] = 0; }
  __syncthreads();
  for (int base = 0; base < n; base += 1024) {
    int i = base + t;
    int v = (i < n) ? deg[i] : 0;
    int x = v;
#pragma unroll
    for (int off = 1; off < 64; off <<= 1) {
      int y = __shfl_up(x, off);
      if (lane >= off) x += y;
    }
    if (lane == 63) wsum[wid] = x;
    __syncthreads();
    int woff = 0;
    for (int w = 0; w < wid; ++w) woff += wsum[w];
    int inc = x + woff + carry_s;
    if (i < n) rowptr[i + 1] = inc;
    __syncthreads();
    if (t == 1023) carry_s = inc;
    __syncthreads();
  }
}

__global__ void scatter_kernel(const int* __restrict__ ei, const int* __restrict__ rowptr,
                               int* __restrict__ cursor, int* __restrict__ sortedSrc, int E_) {
  int e = blockIdx.x * blockDim.x + threadIdx.x;
  if (e >= E_) return;
  int s = ei[e];
  int d = ei[E_ + e];
  int r = atomicAdd(&cursor[d], 1);
  sortedSrc[rowptr[d] + r] = s;
}

// ---------------------------------------------------------------------------
// Per-node projections:
//   PS[n,j] = sum_k h_s[n,k]*W1[j,k] + sum_k h_v[n,k]*W1[j,64+k]
//   PD[n,j] = sum_k h_s[n,k]*W1[j,32+k]
// One wave per node (grid-stride). Lane j owns output feature j.
// ---------------------------------------------------------------------------
__global__ __launch_bounds__(256) void psd_kernel(
    const float* __restrict__ h, const float* __restrict__ W1l,
    float* __restrict__ PS, float* __restrict__ PD, int N_) {
  __shared__ __align__(16) float lds[WPB][64];
  int lane = threadIdx.x & 63, wib = threadIdx.x >> 6;
  int wave = blockIdx.x * WPB + wib, nW = gridDim.x * WPB;
  float ws_[32], wd_[32], wv_[32];
#pragma unroll
  for (int k = 0; k < 32; ++k) {
    ws_[k] = W1l[lane * 99 + k];
    wd_[k] = W1l[lane * 99 + 32 + k];
    wv_[k] = W1l[lane * 99 + 64 + k];
  }
  float* hb = lds[wib];
  for (int n = wave; n < N_; n += nW) {
    if (lane < 16)
      *reinterpret_cast<float4*>(hb + lane * 4) =
          *reinterpret_cast<const float4*>(h + (size_t)n * 64 + lane * 4);
    asm volatile("s_waitcnt lgkmcnt(0)" ::: "memory");
    float ps = 0.f, pd = 0.f;
#pragma unroll
    for (int k4 = 0; k4 < 8; ++k4) {
      float4 a = reinterpret_cast<const float4*>(hb)[k4];
      float4 b = reinterpret_cast<const float4*>(hb + 32)[k4];
      ps = fmaf(a.x, ws_[k4 * 4 + 0], ps); pd = fmaf(a.x, wd_[k4 * 4 + 0], pd);
      ps = fmaf(a.y, ws_[k4 * 4 + 1], ps); pd = fmaf(a.y, wd_[k4 * 4 + 1], pd);
      ps = fmaf(a.z, ws_[k4 * 4 + 2], ps); pd = fmaf(a.z, wd_[k4 * 4 + 2], pd);
      ps = fmaf(a.w, ws_[k4 * 4 + 3], ps); pd = fmaf(a.w, wd_[k4 * 4 + 3], pd);
      ps = fmaf(b.x, wv_[k4 * 4 + 0], ps);
      ps = fmaf(b.y, wv_[k4 * 4 + 1], ps);
      ps = fmaf(b.z, wv_[k4 * 4 + 2], ps);
      ps = fmaf(b.w, wv_[k4 * 4 + 3], ps);
    }
    PS[(size_t)n * 64 + lane] = ps;
    PD[(size_t)n * 64 + lane] = pd;
  }
}

// ---------------------------------------------------------------------------
// Edge aggregation: one wave per dst node. Register accumulation, no atomics.
//   H[n,j] = sum_{e in CSR[n]} silu(PS[src_e,j] + PD[n,j] + Wg_j . geo_e + b1_j)
// geo recomputed from pos (identity orientation => layer-invariant closed form)
// ---------------------------------------------------------------------------
__global__ __launch_bounds__(256) void edge_kernel(
    const float* __restrict__ PS, const float* __restrict__ PD,
    const float* __restrict__ pos, const int* __restrict__ rowptr,
    const int* __restrict__ sortedSrc,
    const float* __restrict__ W1l, const float* __restrict__ b1l,
    float* __restrict__ H, int N_) {
  int lane = threadIdx.x & 63, wib = threadIdx.x >> 6;
  int n = blockIdx.x * WPB + wib;
  if (n >= N_) return;
  float wg0 = W1l[lane * 99 + 96];
  float wg1 = W1l[lane * 99 + 97];
  float wg2 = W1l[lane * 99 + 98];
  float pdj = PD[(size_t)n * 64 + lane] + b1l[lane];
  float px = pos[2 * n], py = pos[2 * n + 1];
  int p = rowptr[n], end = rowptr[n + 1];
  float acc = 0.f;
  if (p < end) {
    int s0 = sortedSrc[p];
    float ps0 = PS[(size_t)s0 * 64 + lane];
    float sx0 = pos[2 * s0], sy0 = pos[2 * s0 + 1];
    while (p + 1 < end) {
      int s1 = sortedSrc[p + 1];
      float ps1 = PS[(size_t)s1 * 64 + lane];
      float sx1 = pos[2 * s1], sy1 = pos[2 * s1 + 1];
      float dx = sx0 - px, dy = sy0 - py;
      float r2 = fmaf(dx, dx, dy * dy);
      float dist = sqrtf(r2) + 1e-6f;
      float inv = (r2 > 0.f) ? 1.0f / r2 : 0.f;
      float c2 = (r2 > 0.f) ? (dx * dx - dy * dy) * inv : 1.0f;
      float s2v = 2.0f * dx * dy * inv;
      float pre = fmaf(wg0, dist, fmaf(wg1, c2, fmaf(wg2, s2v, ps0 + pdj)));
      acc += silu_f(pre);
      s0 = s1; ps0 = ps1; sx0 = sx1; sy0 = sy1; ++p;
    }
    float dx = sx0 - px, dy = sy0 - py;
    float r2 = fmaf(dx, dx, dy * dy);
    float dist = sqrtf(r2) + 1e-6f;
    float inv = (r2 > 0.f) ? 1.0f / r2 : 0.f;
    float c2 = (r2 > 0.f) ? (dx * dx - dy * dy) * inv : 1.0f;
    float s2v = 2.0f * dx * dy * inv;
    float pre = fmaf(wg0, dist, fmaf(wg1, c2, fmaf(wg2, s2v, ps0 + pdj)));
    acc += silu_f(pre);
  }
  H[(size_t)n * 64 + lane] = acc;
}

// ---------------------------------------------------------------------------
// Node update: h[n,:] += W2 . H[n,:] + deg(n)*b2   (in place; residual folded)
// ---------------------------------------------------------------------------
__global__ __launch_bounds__(256) void out_kernel(
    float* __restrict__ h, const float* __restrict__ H,
    const int* __restrict__ rowptr,
    const float* __restrict__ W2l, const float* __restrict__ b2l, int N_) {
  __shared__ __align__(16) float lds[WPB][64];
  int lane = threadIdx.x & 63, wib = threadIdx.x >> 6;
  int wave = blockIdx.x * WPB + wib, nW = gridDim.x * WPB;
  float w2[64];
#pragma unroll
  for (int k = 0; k < 64; ++k) w2[k] = W2l[lane * 64 + k];
  float bb2 = b2l[lane];
  float* Hb = lds[wib];
  for (int n = wave; n < N_; n += nW) {
    if (lane < 16)
      *reinterpret_cast<float4*>(Hb + lane * 4) =
          *reinterpret_cast<const float4*>(H + (size_t)n * 64 + lane * 4);
    asm volatile("s_waitcnt lgkmcnt(0)" ::: "memory");
    float acc = 0.f;
#pragma unroll
    for (int k4 = 0; k4 < 16; ++k4) {
      float4 m = reinterpret_cast<const float4*>(Hb)[k4];
      acc = fmaf(m.x, w2[k4 * 4 + 0], acc);
      acc = fmaf(m.y, w2[k4 * 4 + 1], acc);
      acc = fmaf(m.z, w2[k4 * 4 + 2], acc);
      acc = fmaf(m.w, w2[k4 * 4 + 3], acc);
    }
    float deg = (float)(rowptr[n + 1] - rowptr[n]);
    h[(size_t)n * 64 + lane] += acc + deg * bb2;
  }
}

// ---------------------------------------------------------------------------
// Final: de-interleave h into d_out = [h_s (N*32) | h_v (N*32)]
// ---------------------------------------------------------------------------
__global__ void final_kernel(const float* __restrict__ h, float* __restrict__ out, int N_) {
  int tid = blockIdx.x * blockDim.x + threadIdx.x;
  int n = tid >> 5;
  int j = tid & 31;
  if (n >= N_) return;
  out[(size_t)n * 32 + j] = h[(size_t)n * 64 + j];
  out[(size_t)N_ * 32 + (size_t)n * 32 + j] = h[(size_t)n * 64 + 32 + j];
}

extern "C" void kernel_launch(void* const* d_in, const int* in_sizes, int n_in,
                              void* d_out, int out_size, void* d_ws, size_t ws_size,
                              hipStream_t stream) {
  const float* pos      = (const float*)d_in[0];
  const float* redshift = (const float*)d_in[1];
  const float* shapes   = (const float*)d_in[2];
  const int*   ei       = (const int*)d_in[3];
  const float* enc_s_w  = (const float*)d_in[4];
  const float* enc_s_b  = (const float*)d_in[5];
  const float* enc_v_w  = (const float*)d_in[6];
  const float* W1       = (const float*)d_in[7];
  const float* b1       = (const float*)d_in[8];
  const float* W2       = (const float*)d_in[9];
  const float* b2       = (const float*)d_in[10];

  const int N_ = in_sizes[1];      // 50000
  const int E_ = in_sizes[3] / 2;  // 1000000

  // Workspace layout (~56 MB)
  float* h      = (float*)d_ws;               // N*64
  float* PS     = h + (size_t)N_ * 64;        // N*64
  float* PD     = PS + (size_t)N_ * 64;       // N*64
  float* Hbuf   = PD + (size_t)N_ * 64;       // N*64
  int* rowptr   = (int*)(Hbuf + (size_t)N_ * 64);  // N+1
  int* deg      = rowptr + (N_ + 1);          // N
  int* cursor   = deg + N_;                   // N
  int* sortedSrc= cursor + N_;                // E

  encode_kernel<<<dim3((N_ * 32 + 255) / 256), dim3(256), 0, stream>>>(
      redshift, shapes, enc_s_w, enc_s_b, enc_v_w, h, N_);

  // CSR build (once — edge list and geometry are layer-invariant)
  zero_kernel<<<dim3((2 * N_ + 255) / 256), dim3(256), 0, stream>>>(deg, 2 * N_);
  deg_kernel<<<dim3((E_ + 255) / 256), dim3(256), 0, stream>>>(ei, deg, E_);
  scan_kernel<<<dim3(1), dim3(1024), 0, stream>>>(deg, rowptr, N_);
  scatter_kernel<<<dim3((E_ + 255) / 256), dim3(256), 0, stream>>>(ei, rowptr, cursor, sortedSrc, E_);

  const int nodeBlocks = (N_ + WPB - 1) / WPB;  // one wave per node
  for (int l = 0; l < 3; ++l) {
    const float* W1l = W1 + (size_t)l * 64 * 99;
    const float* b1l = b1 + (size_t)l * 64;
    const float* W2l = W2 + (size_t)l * 64 * 64;
    const float* b2l = b2 + (size_t)l * 64;
    psd_kernel<<<dim3(2048), dim3(256), 0, stream>>>(h, W1l, PS, PD, N_);
    edge_kernel<<<dim3(nodeBlocks), dim3(256), 0, stream>>>(
        PS, PD, pos, rowptr, sortedSrc, W1l, b1l, Hbuf, N_);
    out_kernel<<<dim3(2048), dim3(256), 0, stream>>>(h, Hbuf, rowptr, W2l, b2l, N_);
  }

  final_kernel<<<dim3((N_ * 32 + 255) / 256), dim3(256), 0, stream>>>(h, (float*)d_out, N_);
}

// Round 3
// 598.588 us; speedup vs baseline: 3.8620x; 1.1766x over previous
//
#include <hip/hip_runtime.h>
#include <hip/hip_bf16.h>

#define WPB 4  // waves per block (256 threads)

__device__ __forceinline__ float silu_f(float x) { return x / (1.0f + __expf(-x)); }
__device__ __forceinline__ int rfl(int x) { return __builtin_amdgcn_readfirstlane(x); }

// ---------------------------------------------------------------------------
// Encode: h_s = relu(redshift * enc_s_w^T + b), h_v = shapes @ enc_v_w^T
// Node layout: h[n*64 + 0..31] = h_s, h[n*64 + 32..63] = h_v
// ---------------------------------------------------------------------------
__global__ void encode_kernel(const float* __restrict__ redshift,
                              const float* __restrict__ shapes,
                              const float* __restrict__ enc_s_w,
                              const float* __restrict__ enc_s_b,
                              const float* __restrict__ enc_v_w,
                              float* __restrict__ h, int N_) {
  int tid = blockIdx.x * blockDim.x + threadIdx.x;
  int n = tid >> 5;
  int j = tid & 31;
  if (n >= N_) return;
  float r = redshift[n];
  float hs = fmaxf(fmaf(r, enc_s_w[j], enc_s_b[j]), 0.0f);
  float x0 = shapes[n * 2 + 0];
  float x1 = shapes[n * 2 + 1];
  float hv = fmaf(x0, enc_v_w[j * 2 + 0], x1 * enc_v_w[j * 2 + 1]);
  h[(size_t)n * 64 + j] = hs;
  h[(size_t)n * 64 + 32 + j] = hv;
}

__global__ void zero_kernel(int* __restrict__ p, int n) {
  int i = blockIdx.x * blockDim.x + threadIdx.x;
  if (i < n) p[i] = 0;
}

// ---------------------------------------------------------------------------
// CSR build (once): degree count, prefix scan, scatter (src + geometry).
// ---------------------------------------------------------------------------
__global__ void deg_kernel(const int* __restrict__ ei, int* __restrict__ deg, int E_) {
  int e = blockIdx.x * blockDim.x + threadIdx.x;
  if (e < E_) atomicAdd(&deg[ei[E_ + e]], 1);
}

// single block, 1024 threads; wave-scan + cross-wave + carry
__global__ void scan_kernel(const int* __restrict__ deg, int* __restrict__ rowptr, int n) {
  __shared__ int wsum[16];
  __shared__ int carry_s;
  int t = threadIdx.x, lane = t & 63, wid = t >> 6;
  if (t == 0) { carry_s = 0; rowptr[0] = 0; }
  __syncthreads();
  for (int base = 0; base < n; base += 1024) {
    int i = base + t;
    int v = (i < n) ? deg[i] : 0;
    int x = v;
#pragma unroll
    for (int off = 1; off < 64; off <<= 1) {
      int y = __shfl_up(x, off);
      if (lane >= off) x += y;
    }
    if (lane == 63) wsum[wid] = x;
    __syncthreads();
    int woff = 0;
    for (int w = 0; w < wid; ++w) woff += wsum[w];
    int inc = x + woff + carry_s;
    if (i < n) rowptr[i + 1] = inc;
    __syncthreads();
    if (t == 1023) carry_s = inc;
    __syncthreads();
  }
}

// Scatter src by dst AND precompute layer-invariant geometry per sorted edge:
// geo = [dist, cos(2*phi), sin(2*phi)] with identity orientation closed form.
__global__ void scatter_kernel(const int* __restrict__ ei, const float* __restrict__ pos,
                               const int* __restrict__ rowptr, int* __restrict__ cursor,
                               int* __restrict__ sortedSrc,
                               float* __restrict__ distA, float* __restrict__ c2A,
                               float* __restrict__ s2A, int E_) {
  int e = blockIdx.x * blockDim.x + threadIdx.x;
  if (e >= E_) return;
  int s = ei[e];
  int d = ei[E_ + e];
  int r = atomicAdd(&cursor[d], 1);
  int idx = rowptr[d] + r;
  sortedSrc[idx] = s;
  float dx = pos[s * 2 + 0] - pos[d * 2 + 0];
  float dy = pos[s * 2 + 1] - pos[d * 2 + 1];
  float r2 = fmaf(dx, dx, dy * dy);
  float dist = sqrtf(r2) + 1e-6f;
  float c2 = 1.0f, s2 = 0.0f;
  if (r2 > 0.0f) {
    float inv = 1.0f / r2;
    c2 = (dx * dx - dy * dy) * inv;
    s2 = 2.0f * dx * dy * inv;
  }
  distA[idx] = dist;
  c2A[idx] = c2;
  s2A[idx] = s2;
}

// ---------------------------------------------------------------------------
// Per-node projections (W1 split by operand; b1 folded into PDB):
//   PS[n,j]  = sum_k h_s[n,k]*W1[j,k] + sum_k h_v[n,k]*W1[j,64+k]
//   PDB[n,j] = sum_k h_s[n,k]*W1[j,32+k] + b1[j]
// Weights via coalesced LDS bounce; h read at uniform addresses (s_load).
// ---------------------------------------------------------------------------
__global__ __launch_bounds__(256) void psd_kernel(
    const float* __restrict__ h, const float* __restrict__ W1l,
    const float* __restrict__ b1l,
    float* __restrict__ PS, float* __restrict__ PDB, int N_) {
  __shared__ float wsh[99 * 64];
  int t = threadIdx.x;
  for (int i = t; i < 99 * 64; i += 256) wsh[i] = W1l[i];
  __syncthreads();
  int lane = t & 63, wib = t >> 6;
  float ws_[32], wd_[32], wv_[32];
#pragma unroll
  for (int k = 0; k < 32; ++k) {
    ws_[k] = wsh[lane * 99 + k];
    wd_[k] = wsh[lane * 99 + 32 + k];
    wv_[k] = wsh[lane * 99 + 64 + k];
  }
  float bb1 = b1l[lane];
  int wave0 = rfl(blockIdx.x * WPB + wib);
  int nW = gridDim.x * WPB;
  for (int n = wave0; n < N_; n += nW) {
    const float* hn = h + (size_t)n * 64;
    float ps0 = 0.f, ps1 = 0.f, ps2 = 0.f, ps3 = 0.f, pd0 = 0.f, pd1 = 0.f;
#pragma unroll
    for (int k = 0; k < 32; k += 4) {
      float a0 = hn[k], a1 = hn[k + 1], a2 = hn[k + 2], a3 = hn[k + 3];
      float v0 = hn[32 + k], v1 = hn[33 + k], v2 = hn[34 + k], v3 = hn[35 + k];
      ps0 = fmaf(a0, ws_[k], ps0);     pd0 = fmaf(a0, wd_[k], pd0);
      ps1 = fmaf(a1, ws_[k + 1], ps1); pd1 = fmaf(a1, wd_[k + 1], pd1);
      ps2 = fmaf(a2, ws_[k + 2], ps2); pd0 = fmaf(a2, wd_[k + 2], pd0);
      ps3 = fmaf(a3, ws_[k + 3], ps3); pd1 = fmaf(a3, wd_[k + 3], pd1);
      ps0 = fmaf(v0, wv_[k], ps0);
      ps1 = fmaf(v1, wv_[k + 1], ps1);
      ps2 = fmaf(v2, wv_[k + 2], ps2);
      ps3 = fmaf(v3, wv_[k + 3], ps3);
    }
    PS[(size_t)n * 64 + lane] = (ps0 + ps1) + (ps2 + ps3);
    PDB[(size_t)n * 64 + lane] = (pd0 + pd1) + bb1;
  }
}

// ---------------------------------------------------------------------------
// Fused edge aggregation + W2 update. One wave per dst node (grid-stride).
//   acc[j] = sum_{e in CSR[n]} silu(PS[src_e,j] + PDB[n,j] + Wg_j . geo_e)
//   h[n,:] += W2 . acc + deg(n)*b2
// Scalarized: n/p/end/src uniform (SGPR) -> s_load for indices+geo, SGPR-base
// gathers for PS. Geometry is precomputed (no pos, no sqrt/rcp per layer).
// ---------------------------------------------------------------------------
__global__ __launch_bounds__(256) void edgeout_kernel(
    const float* __restrict__ PS, const float* __restrict__ PDB,
    const int* __restrict__ rowptr, const int* __restrict__ sortedSrc,
    const float* __restrict__ distA, const float* __restrict__ c2A,
    const float* __restrict__ s2A,
    const float* __restrict__ W1l, const float* __restrict__ W2l,
    const float* __restrict__ b2l,
    float* __restrict__ h, int N_) {
  __shared__ float w2sh[64 * 65];
  __shared__ __align__(16) float accb[WPB][64];
  int t = threadIdx.x;
  for (int i = t; i < 64 * 64; i += 256) w2sh[(i >> 6) * 65 + (i & 63)] = W2l[i];
  __syncthreads();
  int lane = t & 63, wib = t >> 6;
  float w2[64];
#pragma unroll
  for (int k = 0; k < 64; ++k) w2[k] = w2sh[lane * 65 + k];
  float wg0 = W1l[lane * 99 + 96];
  float wg1 = W1l[lane * 99 + 97];
  float wg2 = W1l[lane * 99 + 98];
  float bb2 = b2l[lane];
  int wave0 = rfl(blockIdx.x * WPB + wib);
  int nW = gridDim.x * WPB;
  float* ab = accb[wib];
  for (int n = wave0; n < N_; n += nW) {
    float pdj = PDB[(size_t)n * 64 + lane];
    int p = rfl(rowptr[n]);
    int end = rfl(rowptr[n + 1]);
    float degf = (float)(end - p);
    float acc0 = 0.f, acc1 = 0.f;
    for (; p + 2 <= end; p += 2) {
      int s0 = rfl(sortedSrc[p]);
      int s1 = rfl(sortedSrc[p + 1]);
      float d0 = distA[p], d1 = distA[p + 1];
      float cA = c2A[p], cB = c2A[p + 1];
      float sA = s2A[p], sB = s2A[p + 1];
      float ps0 = PS[(size_t)s0 * 64 + lane];
      float ps1 = PS[(size_t)s1 * 64 + lane];
      float pre0 = fmaf(wg0, d0, fmaf(wg1, cA, fmaf(wg2, sA, ps0 + pdj)));
      float pre1 = fmaf(wg0, d1, fmaf(wg1, cB, fmaf(wg2, sB, ps1 + pdj)));
      acc0 += silu_f(pre0);
      acc1 += silu_f(pre1);
    }
    if (p < end) {
      int s0 = rfl(sortedSrc[p]);
      float pre0 = fmaf(wg0, distA[p],
                   fmaf(wg1, c2A[p],
                   fmaf(wg2, s2A[p], PS[(size_t)s0 * 64 + lane] + pdj)));
      acc0 += silu_f(pre0);
    }
    ab[lane] = acc0 + acc1;
    asm volatile("s_waitcnt lgkmcnt(0)" ::: "memory");
    // W2 matvec on the wave's private acc row (broadcast reads, conflict-free)
    float o0 = 0.f, o1 = 0.f;
#pragma unroll
    for (int k4 = 0; k4 < 16; k4 += 2) {
      float4 m0 = reinterpret_cast<const float4*>(ab)[k4];
      float4 m1 = reinterpret_cast<const float4*>(ab)[k4 + 1];
      o0 = fmaf(m0.x, w2[k4 * 4 + 0], o0);
      o0 = fmaf(m0.y, w2[k4 * 4 + 1], o0);
      o0 = fmaf(m0.z, w2[k4 * 4 + 2], o0);
      o0 = fmaf(m0.w, w2[k4 * 4 + 3], o0);
      o1 = fmaf(m1.x, w2[k4 * 4 + 4], o1);
      o1 = fmaf(m1.y, w2[k4 * 4 + 5], o1);
      o1 = fmaf(m1.z, w2[k4 * 4 + 6], o1);
      o1 = fmaf(m1.w, w2[k4 * 4 + 7], o1);
    }
    asm volatile("s_waitcnt lgkmcnt(0)" ::: "memory");
    h[(size_t)n * 64 + lane] += (o0 + o1) + degf * bb2;
  }
}

// ---------------------------------------------------------------------------
// Final: de-interleave h into d_out = [h_s (N*32) | h_v (N*32)]
// ---------------------------------------------------------------------------
__global__ void final_kernel(const float* __restrict__ h, float* __restrict__ out, int N_) {
  int tid = blockIdx.x * blockDim.x + threadIdx.x;
  int n = tid >> 5;
  int j = tid & 31;
  if (n >= N_) return;
  out[(size_t)n * 32 + j] = h[(size_t)n * 64 + j];
  out[(size_t)N_ * 32 + (size_t)n * 32 + j] = h[(size_t)n * 64 + 32 + j];
}

extern "C" void kernel_launch(void* const* d_in, const int* in_sizes, int n_in,
                              void* d_out, int out_size, void* d_ws, size_t ws_size,
                              hipStream_t stream) {
  const float* pos      = (const float*)d_in[0];
  const float* redshift = (const float*)d_in[1];
  const float* shapes   = (const float*)d_in[2];
  const int*   ei       = (const int*)d_in[3];
  const float* enc_s_w  = (const float*)d_in[4];
  const float* enc_s_b  = (const float*)d_in[5];
  const float* enc_v_w  = (const float*)d_in[6];
  const float* W1       = (const float*)d_in[7];
  const float* b1       = (const float*)d_in[8];
  const float* W2       = (const float*)d_in[9];
  const float* b2       = (const float*)d_in[10];

  const int N_ = in_sizes[1];      // 50000
  const int E_ = in_sizes[3] / 2;  // 1000000

  // Workspace layout (~55 MB)
  float* h     = (float*)d_ws;                 // N*64
  float* PS    = h + (size_t)N_ * 64;          // N*64
  float* PDB   = PS + (size_t)N_ * 64;         // N*64
  float* distA = PDB + (size_t)N_ * 64;        // E
  float* c2A   = distA + E_;                   // E
  float* s2A   = c2A + E_;                     // E
  int* rowptr  = (int*)(s2A + E_);             // N+1
  int* deg     = rowptr + (N_ + 1);            // N
  int* cursor  = deg + N_;                     // N
  int* sortedSrc = cursor + N_;                // E

  encode_kernel<<<dim3((N_ * 32 + 255) / 256), dim3(256), 0, stream>>>(
      redshift, shapes, enc_s_w, enc_s_b, enc_v_w, h, N_);

  // CSR build + layer-invariant geometry (once)
  zero_kernel<<<dim3((2 * N_ + 255) / 256), dim3(256), 0, stream>>>(deg, 2 * N_);
  deg_kernel<<<dim3((E_ + 255) / 256), dim3(256), 0, stream>>>(ei, deg, E_);
  scan_kernel<<<dim3(1), dim3(1024), 0, stream>>>(deg, rowptr, N_);
  scatter_kernel<<<dim3((E_ + 255) / 256), dim3(256), 0, stream>>>(
      ei, pos, rowptr, cursor, sortedSrc, distA, c2A, s2A, E_);

  for (int l = 0; l < 3; ++l) {
    const float* W1l = W1 + (size_t)l * 64 * 99;
    const float* b1l = b1 + (size_t)l * 64;
    const float* W2l = W2 + (size_t)l * 64 * 64;
    const float* b2l = b2 + (size_t)l * 64;
    psd_kernel<<<dim3(1024), dim3(256), 0, stream>>>(h, W1l, b1l, PS, PDB, N_);
    edgeout_kernel<<<dim3(2048), dim3(256), 0, stream>>>(
        PS, PDB, rowptr, sortedSrc, distA, c2A, s2A, W1l, W2l, b2l, h, N_);
  }

  final_kernel<<<dim3((N_ * 32 + 255) / 256), dim3(256), 0, stream>>>(h, (float*)d_out, N_);
}

// Round 4
// 491.114 us; speedup vs baseline: 4.7072x; 1.2188x over previous
//
#include <hip/hip_runtime.h>
#include <hip/hip_bf16.h>

#define WPB 4  // waves per block (256 threads)

__device__ __forceinline__ float silu_f(float x) {
  return x * __builtin_amdgcn_rcpf(1.0f + __expf(-x));
}
__device__ __forceinline__ int rfl(int x) { return __builtin_amdgcn_readfirstlane(x); }
__device__ __forceinline__ float readlane_f(float v, int l) {
  return __int_as_float(__builtin_amdgcn_readlane(__float_as_int(v), l));
}

// ---------------------------------------------------------------------------
// Encode directly into d_out (planar): out[0..N*32) = h_s, out[N*32..) = h_v
// ---------------------------------------------------------------------------
__global__ void encode_kernel(const float* __restrict__ redshift,
                              const float* __restrict__ shapes,
                              const float* __restrict__ enc_s_w,
                              const float* __restrict__ enc_s_b,
                              const float* __restrict__ enc_v_w,
                              float* __restrict__ hout, int N_) {
  int tid = blockIdx.x * blockDim.x + threadIdx.x;
  int n = tid >> 5;
  int j = tid & 31;
  if (n >= N_) return;
  float r = redshift[n];
  float hs = fmaxf(fmaf(r, enc_s_w[j], enc_s_b[j]), 0.0f);
  float x0 = shapes[n * 2 + 0];
  float x1 = shapes[n * 2 + 1];
  float hv = fmaf(x0, enc_v_w[j * 2 + 0], x1 * enc_v_w[j * 2 + 1]);
  hout[(size_t)n * 32 + j] = hs;
  hout[(size_t)N_ * 32 + (size_t)n * 32 + j] = hv;
}

__global__ void zero_kernel(int* __restrict__ p, int n) {
  int i = blockIdx.x * blockDim.x + threadIdx.x;
  if (i < n) p[i] = 0;
}

// ---------------------------------------------------------------------------
// CSR build (once): degree, hierarchical scan (3 kernels), scatter.
// ---------------------------------------------------------------------------
__global__ void deg_kernel(const int* __restrict__ ei, int* __restrict__ deg, int E_) {
  int e = blockIdx.x * blockDim.x + threadIdx.x;
  if (e < E_) atomicAdd(&deg[ei[E_ + e]], 1);
}

__global__ __launch_bounds__(1024) void scanA_kernel(const int* __restrict__ deg,
                                                     int* __restrict__ rowptr,
                                                     int* __restrict__ bsum, int n) {
  __shared__ int wsum[16];
  int t = threadIdx.x, lane = t & 63, wid = t >> 6;
  int i = blockIdx.x * 1024 + t;
  int v = (i < n) ? deg[i] : 0;
  int x = v;
#pragma unroll
  for (int off = 1; off < 64; off <<= 1) {
    int y = __shfl_up(x, off);
    if (lane >= off) x += y;
  }
  if (lane == 63) wsum[wid] = x;
  __syncthreads();
  if (t == 0) {
    int run = 0;
#pragma unroll
    for (int w = 0; w < 16; ++w) { int s = wsum[w]; wsum[w] = run; run += s; }
  }
  __syncthreads();
  int inc = x + wsum[wid];
  if (i < n) rowptr[i + 1] = inc;  // inclusive within block
  if (t == 1023) bsum[blockIdx.x] = inc;
}

__global__ __launch_bounds__(1024) void scanB_kernel(int* __restrict__ bsum, int nb) {
  __shared__ int wsum[16];
  int t = threadIdx.x, lane = t & 63, wid = t >> 6;
  int v = (t < nb) ? bsum[t] : 0;
  int x = v;
#pragma unroll
  for (int off = 1; off < 64; off <<= 1) {
    int y = __shfl_up(x, off);
    if (lane >= off) x += y;
  }
  if (lane == 63) wsum[wid] = x;
  __syncthreads();
  if (t == 0) {
    int run = 0;
#pragma unroll
    for (int w = 0; w < 16; ++w) { int s = wsum[w]; wsum[w] = run; run += s; }
  }
  __syncthreads();
  if (t < nb) bsum[t] = x - v + wsum[wid];  // exclusive
}

__global__ void scanC_kernel(int* __restrict__ rowptr, const int* __restrict__ bsum, int n) {
  int i = blockIdx.x * blockDim.x + threadIdx.x;
  if (i == 0) rowptr[0] = 0;
  if (i < n) rowptr[i + 1] += bsum[i >> 10];
}

// Scatter into dst-sorted order: edata = (dist, cos2phi, sin2phi, src_bits)
__global__ void scatter_kernel(const int* __restrict__ ei, const float* __restrict__ pos,
                               const int* __restrict__ rowptr, int* __restrict__ cursor,
                               float4* __restrict__ edata, int* __restrict__ dstS, int E_) {
  int e = blockIdx.x * blockDim.x + threadIdx.x;
  if (e >= E_) return;
  int s = ei[e];
  int d = ei[E_ + e];
  int idx = rowptr[d] + atomicAdd(&cursor[d], 1);
  float dx = pos[s * 2 + 0] - pos[d * 2 + 0];
  float dy = pos[s * 2 + 1] - pos[d * 2 + 1];
  float r2 = fmaf(dx, dx, dy * dy);
  float dist = sqrtf(r2) + 1e-6f;
  float c2 = 1.0f, s2 = 0.0f;
  if (r2 > 0.0f) {
    float inv = 1.0f / r2;
    c2 = (dx * dx - dy * dy) * inv;
    s2 = 2.0f * dx * dy * inv;
  }
  edata[idx] = make_float4(dist, c2, s2, __int_as_float(s));
  dstS[idx] = d;
}

__global__ void pad_kernel(float4* __restrict__ edata, int* __restrict__ dstS,
                           int E_, int N_) {
  int i = E_ + threadIdx.x;
  edata[i] = make_float4(0.f, 0.f, 0.f, __int_as_float(0));
  dstS[i] = N_;  // sentinel row of H/PDB (allocated, never read back)
}

// ---------------------------------------------------------------------------
// Per-node projections + H zeroing (fused).
//   PS[n,j]  = h_s[n]·W1[j,0:32] + h_v[n]·W1[j,64:96]
//   PDB[n,j] = h_s[n]·W1[j,32:64] + b1[j]
// ---------------------------------------------------------------------------
__global__ __launch_bounds__(256) void psd_kernel(
    const float* __restrict__ hout, const float* __restrict__ W1l,
    const float* __restrict__ b1l,
    float* __restrict__ PS, float* __restrict__ PDB, float* __restrict__ H, int N_) {
  __shared__ float wsh[99 * 64];
  int t = threadIdx.x;
  for (int i = t; i < 99 * 64; i += 256) wsh[i] = W1l[i];
  __syncthreads();
  int lane = t & 63, wib = t >> 6;
  float ws_[32], wd_[32], wv_[32];
#pragma unroll
  for (int k = 0; k < 32; ++k) {
    ws_[k] = wsh[lane * 99 + k];
    wd_[k] = wsh[lane * 99 + 32 + k];
    wv_[k] = wsh[lane * 99 + 64 + k];
  }
  float bb1 = b1l[lane];
  int wave0 = rfl(blockIdx.x * WPB + wib);
  int nW = gridDim.x * WPB;
  const float* hvbase = hout + (size_t)N_ * 32;
  for (int n = wave0; n < N_; n += nW) {
    const float* hs = hout + (size_t)n * 32;
    const float* hv = hvbase + (size_t)n * 32;
    float ps0 = 0.f, ps1 = 0.f, ps2 = 0.f, ps3 = 0.f, pd0 = 0.f, pd1 = 0.f;
#pragma unroll
    for (int k = 0; k < 32; k += 4) {
      float a0 = hs[k], a1 = hs[k + 1], a2 = hs[k + 2], a3 = hs[k + 3];
      float v0 = hv[k], v1 = hv[k + 1], v2 = hv[k + 2], v3 = hv[k + 3];
      ps0 = fmaf(a0, ws_[k], ps0);     pd0 = fmaf(a0, wd_[k], pd0);
      ps1 = fmaf(a1, ws_[k + 1], ps1); pd1 = fmaf(a1, wd_[k + 1], pd1);
      ps2 = fmaf(a2, ws_[k + 2], ps2); pd0 = fmaf(a2, wd_[k + 2], pd0);
      ps3 = fmaf(a3, ws_[k + 3], ps3); pd1 = fmaf(a3, wd_[k + 3], pd1);
      ps0 = fmaf(v0, wv_[k], ps0);
      ps1 = fmaf(v1, wv_[k + 1], ps1);
      ps2 = fmaf(v2, wv_[k + 2], ps2);
      ps3 = fmaf(v3, wv_[k + 3], ps3);
    }
    PS[(size_t)n * 64 + lane] = (ps0 + ps1) + (ps2 + ps3);
    PDB[(size_t)n * 64 + lane] = (pd0 + pd1) + bb1;
    H[(size_t)n * 64 + lane] = 0.0f;
  }
}

// ---------------------------------------------------------------------------
// Edge phase: one wave per 64-edge chunk of the dst-sorted edge array.
// Edge scalars arrive in ONE coalesced float4 + one int load; inner loop uses
// v_readlane (no loads for edge data). Segment flushes via wave-wide f32
// atomicAdd into H (~4 per chunk; boundaries from one ballot mask).
// ---------------------------------------------------------------------------
__global__ __launch_bounds__(256) void edge_kernel(
    const float* __restrict__ PS, const float* __restrict__ PDB,
    const float4* __restrict__ edata, const int* __restrict__ dstS,
    const float* __restrict__ W1l, float* __restrict__ H, int nchunk) {
  int lane = threadIdx.x & 63, wib = threadIdx.x >> 6;
  int chunk = blockIdx.x * WPB + wib;
  if (chunk >= nchunk) return;
  int base = chunk << 6;
  float wg0 = W1l[lane * 99 + 96];
  float wg1 = W1l[lane * 99 + 97];
  float wg2 = W1l[lane * 99 + 98];
  float4 ed = edata[base + lane];
  int dv = dstS[base + lane];
  int sv = __float_as_int(ed.w);
  int dprev = __shfl_up(dv, 1);
  unsigned long long bmask = __ballot(dv != dprev) & ~1ull;
  int dcur = rfl(dv);
  float pdj = PDB[(size_t)dcur * 64 + lane];
  float acc = 0.0f;
#pragma unroll
  for (int e = 0; e < 64; ++e) {
    if ((bmask >> e) & 1ull) {  // wave-uniform branch (~1 in 20)
      atomicAdd(H + (size_t)dcur * 64 + lane, acc);
      acc = 0.0f;
      dcur = __builtin_amdgcn_readlane(dv, e);
      pdj = PDB[(size_t)dcur * 64 + lane];
    }
    int se = __builtin_amdgcn_readlane(sv, e);
    float di = readlane_f(ed.x, e);
    float c2 = readlane_f(ed.y, e);
    float s2 = readlane_f(ed.z, e);
    float ps = PS[(size_t)se * 64 + lane];
    float pre = fmaf(wg0, di, fmaf(wg1, c2, fmaf(wg2, s2, ps + pdj)));
    acc += silu_f(pre);
  }
  atomicAdd(H + (size_t)dcur * 64 + lane, acc);
}

// ---------------------------------------------------------------------------
// Node update (planar h in d_out): h[n,:] += W2 . H[n,:] + deg(n)*b2
// ---------------------------------------------------------------------------
__global__ __launch_bounds__(256) void out_kernel(
    float* __restrict__ hout, const float* __restrict__ H,
    const int* __restrict__ deg,
    const float* __restrict__ W2l, const float* __restrict__ b2l, int N_) {
  __shared__ float w2sh[64 * 65];
  __shared__ __align__(16) float Hb[WPB][64];
  int t = threadIdx.x;
  for (int i = t; i < 64 * 64; i += 256) w2sh[(i >> 6) * 65 + (i & 63)] = W2l[i];
  __syncthreads();
  int lane = t & 63, wib = t >> 6;
  float w2[64];
#pragma unroll
  for (int k = 0; k < 64; ++k) w2[k] = w2sh[lane * 65 + k];
  float bb2 = b2l[lane];
  int wave0 = rfl(blockIdx.x * WPB + wib);
  int nW = gridDim.x * WPB;
  float* Hrow = Hb[wib];
  size_t plane = (size_t)(lane >> 5) * ((size_t)N_ * 32);
  for (int n = wave0; n < N_; n += nW) {
    if (lane < 16)
      *reinterpret_cast<float4*>(Hrow + lane * 4) =
          *reinterpret_cast<const float4*>(H + (size_t)n * 64 + lane * 4);
    asm volatile("s_waitcnt lgkmcnt(0)" ::: "memory");
    float o0 = 0.f, o1 = 0.f;
#pragma unroll
    for (int k4 = 0; k4 < 16; k4 += 2) {
      float4 m0 = reinterpret_cast<const float4*>(Hrow)[k4];
      float4 m1 = reinterpret_cast<const float4*>(Hrow)[k4 + 1];
      o0 = fmaf(m0.x, w2[k4 * 4 + 0], o0);
      o0 = fmaf(m0.y, w2[k4 * 4 + 1], o0);
      o0 = fmaf(m0.z, w2[k4 * 4 + 2], o0);
      o0 = fmaf(m0.w, w2[k4 * 4 + 3], o0);
      o1 = fmaf(m1.x, w2[k4 * 4 + 4], o1);
      o1 = fmaf(m1.y, w2[k4 * 4 + 5], o1);
      o1 = fmaf(m1.z, w2[k4 * 4 + 6], o1);
      o1 = fmaf(m1.w, w2[k4 * 4 + 7], o1);
    }
    asm volatile("s_waitcnt lgkmcnt(0)" ::: "memory");
    float degf = (float)deg[n];
    hout[plane + (size_t)n * 32 + (lane & 31)] += (o0 + o1) + degf * bb2;
  }
}

extern "C" void kernel_launch(void* const* d_in, const int* in_sizes, int n_in,
                              void* d_out, int out_size, void* d_ws, size_t ws_size,
                              hipStream_t stream) {
  const float* pos      = (const float*)d_in[0];
  const float* redshift = (const float*)d_in[1];
  const float* shapes   = (const float*)d_in[2];
  const int*   ei       = (const int*)d_in[3];
  const float* enc_s_w  = (const float*)d_in[4];
  const float* enc_s_b  = (const float*)d_in[5];
  const float* enc_v_w  = (const float*)d_in[6];
  const float* W1       = (const float*)d_in[7];
  const float* b1       = (const float*)d_in[8];
  const float* W2       = (const float*)d_in[9];
  const float* b2       = (const float*)d_in[10];

  const int N_ = in_sizes[1];      // 50000
  const int E_ = in_sizes[3] / 2;  // 1000000
  const int nchunk = (E_ + 63) / 64;
  const int padE = nchunk * 64;

  // Workspace (~59 MB): edata first (16B alignment from d_ws base)
  float4* edata = (float4*)d_ws;                       // padE
  float* PS     = (float*)(edata + padE);              // N*64
  float* PDB    = PS + (size_t)N_ * 64;                // (N+1)*64 (pad row)
  float* H      = PDB + (size_t)(N_ + 1) * 64;         // (N+1)*64 (pad row)
  int* dstS     = (int*)(H + (size_t)(N_ + 1) * 64);   // padE
  int* rowptr   = dstS + padE;                         // N+1
  int* deg      = rowptr + (N_ + 1);                   // N
  int* cursor   = deg + N_;                            // N (adjacent to deg)
  int* bsum     = cursor + N_;                         // 1024

  float* hout = (float*)d_out;  // planar h lives in d_out

  encode_kernel<<<dim3((N_ * 32 + 255) / 256), dim3(256), 0, stream>>>(
      redshift, shapes, enc_s_w, enc_s_b, enc_v_w, hout, N_);

  // CSR build + layer-invariant geometry (once)
  zero_kernel<<<dim3((2 * N_ + 255) / 256), dim3(256), 0, stream>>>(deg, 2 * N_);
  deg_kernel<<<dim3((E_ + 255) / 256), dim3(256), 0, stream>>>(ei, deg, E_);
  const int nbA = (N_ + 1023) / 1024;
  scanA_kernel<<<dim3(nbA), dim3(1024), 0, stream>>>(deg, rowptr, bsum, N_);
  scanB_kernel<<<dim3(1), dim3(1024), 0, stream>>>(bsum, nbA);
  scanC_kernel<<<dim3((N_ + 255) / 256), dim3(256), 0, stream>>>(rowptr, bsum, N_);
  scatter_kernel<<<dim3((E_ + 255) / 256), dim3(256), 0, stream>>>(
      ei, pos, rowptr, cursor, edata, dstS, E_);
  if (padE > E_)
    pad_kernel<<<dim3(1), dim3(padE - E_), 0, stream>>>(edata, dstS, E_, N_);

  const int edgeBlocks = (nchunk + WPB - 1) / WPB;
  for (int l = 0; l < 3; ++l) {
    const float* W1l = W1 + (size_t)l * 64 * 99;
    const float* b1l = b1 + (size_t)l * 64;
    const float* W2l = W2 + (size_t)l * 64 * 64;
    const float* b2l = b2 + (size_t)l * 64;
    psd_kernel<<<dim3(1024), dim3(256), 0, stream>>>(hout, W1l, b1l, PS, PDB, H, N_);
    edge_kernel<<<dim3(edgeBlocks), dim3(256), 0, stream>>>(
        PS, PDB, edata, dstS, W1l, H, nchunk);
    out_kernel<<<dim3(2048), dim3(256), 0, stream>>>(hout, H, deg, W2l, b2l, N_);
  }
}

// Round 5
// 444.709 us; speedup vs baseline: 5.1984x; 1.1043x over previous
//
#include <hip/hip_runtime.h>
#include <hip/hip_bf16.h>

#define WPB 4   // waves per block (256 threads)
#define TILE 16 // node rows staged per block iteration

__device__ __forceinline__ float silu_f(float x) {
  return x * __builtin_amdgcn_rcpf(1.0f + __expf(-x));
}
__device__ __forceinline__ int rfl(int x) { return __builtin_amdgcn_readfirstlane(x); }
__device__ __forceinline__ float readlane_f(float v, int l) {
  return __int_as_float(__builtin_amdgcn_readlane(__float_as_int(v), l));
}

// ---------------------------------------------------------------------------
// Encode directly into d_out (planar): out[0..N*32) = h_s, out[N*32..) = h_v
// ---------------------------------------------------------------------------
__global__ void encode_kernel(const float* __restrict__ redshift,
                              const float* __restrict__ shapes,
                              const float* __restrict__ enc_s_w,
                              const float* __restrict__ enc_s_b,
                              const float* __restrict__ enc_v_w,
                              float* __restrict__ hout, int N_) {
  int tid = blockIdx.x * blockDim.x + threadIdx.x;
  int n = tid >> 5;
  int j = tid & 31;
  if (n >= N_) return;
  float r = redshift[n];
  float hs = fmaxf(fmaf(r, enc_s_w[j], enc_s_b[j]), 0.0f);
  float x0 = shapes[n * 2 + 0];
  float x1 = shapes[n * 2 + 1];
  float hv = fmaf(x0, enc_v_w[j * 2 + 0], x1 * enc_v_w[j * 2 + 1]);
  hout[(size_t)n * 32 + j] = hs;
  hout[(size_t)N_ * 32 + (size_t)n * 32 + j] = hv;
}

__global__ void zero_kernel(int* __restrict__ p, int n) {
  int i = blockIdx.x * blockDim.x + threadIdx.x;
  if (i < n) p[i] = 0;
}

// ---------------------------------------------------------------------------
// CSR build (once): degree, hierarchical scan, perm-scatter, coalesced geo.
// ---------------------------------------------------------------------------
__global__ void deg_kernel(const int* __restrict__ ei, int* __restrict__ deg, int E_) {
  int e = blockIdx.x * blockDim.x + threadIdx.x;
  if (e < E_) atomicAdd(&deg[ei[E_ + e]], 1);
}

__global__ __launch_bounds__(1024) void scanA_kernel(const int* __restrict__ deg,
                                                     int* __restrict__ rowptr,
                                                     int* __restrict__ bsum, int n) {
  __shared__ int wsum[16];
  int t = threadIdx.x, lane = t & 63, wid = t >> 6;
  int i = blockIdx.x * 1024 + t;
  int v = (i < n) ? deg[i] : 0;
  int x = v;
#pragma unroll
  for (int off = 1; off < 64; off <<= 1) {
    int y = __shfl_up(x, off);
    if (lane >= off) x += y;
  }
  if (lane == 63) wsum[wid] = x;
  __syncthreads();
  if (t == 0) {
    int run = 0;
#pragma unroll
    for (int w = 0; w < 16; ++w) { int s = wsum[w]; wsum[w] = run; run += s; }
  }
  __syncthreads();
  int inc = x + wsum[wid];
  if (i < n) rowptr[i + 1] = inc;  // inclusive within block
  if (t == 1023) bsum[blockIdx.x] = inc;
}

__global__ __launch_bounds__(1024) void scanB_kernel(int* __restrict__ bsum, int nb) {
  __shared__ int wsum[16];
  int t = threadIdx.x, lane = t & 63, wid = t >> 6;
  int v = (t < nb) ? bsum[t] : 0;
  int x = v;
#pragma unroll
  for (int off = 1; off < 64; off <<= 1) {
    int y = __shfl_up(x, off);
    if (lane >= off) x += y;
  }
  if (lane == 63) wsum[wid] = x;
  __syncthreads();
  if (t == 0) {
    int run = 0;
#pragma unroll
    for (int w = 0; w < 16; ++w) { int s = wsum[w]; wsum[w] = run; run += s; }
  }
  __syncthreads();
  if (t < nb) bsum[t] = x - v + wsum[wid];  // exclusive
}

__global__ void scanC_kernel(int* __restrict__ rowptr, const int* __restrict__ bsum, int n) {
  int i = blockIdx.x * blockDim.x + threadIdx.x;
  if (i == 0) rowptr[0] = 0;
  if (i < n) rowptr[i + 1] += bsum[i >> 10];
}

// Phase 1: scatter only the 4-byte edge id into sorted position (in dstS).
__global__ void scatter1_kernel(const int* __restrict__ ei, const int* __restrict__ rowptr,
                                int* __restrict__ cursor, int* __restrict__ perm, int E_) {
  int e = blockIdx.x * blockDim.x + threadIdx.x;
  if (e >= E_) return;
  int d = ei[E_ + e];
  int idx = rowptr[d] + atomicAdd(&cursor[d], 1);
  perm[idx] = e;
}

// Phase 2: coalesced pass over sorted slots; gather ei/pos, write edata+dstS
// coalesced. perm lives in dstS and is overwritten after being read (same
// thread, same slot -> safe).
__global__ void scatter2_kernel(const int* __restrict__ ei, const float* __restrict__ pos,
                                int* __restrict__ permdst, float4* __restrict__ edata,
                                int E_) {
  int p = blockIdx.x * blockDim.x + threadIdx.x;
  if (p >= E_) return;
  int e = permdst[p];
  int s = ei[e];
  int d = ei[E_ + e];
  float dx = pos[s * 2 + 0] - pos[d * 2 + 0];
  float dy = pos[s * 2 + 1] - pos[d * 2 + 1];
  float r2 = fmaf(dx, dx, dy * dy);
  float dist = sqrtf(r2) + 1e-6f;
  float c2 = 1.0f, s2 = 0.0f;
  if (r2 > 0.0f) {
    float inv = 1.0f / r2;
    c2 = (dx * dx - dy * dy) * inv;
    s2 = 2.0f * dx * dy * inv;
  }
  edata[p] = make_float4(dist, c2, s2, __int_as_float(s));
  permdst[p] = d;
}

__global__ void pad_kernel(float4* __restrict__ edata, int* __restrict__ dstS,
                           int E_, int N_) {
  int i = E_ + threadIdx.x;
  edata[i] = make_float4(0.f, 0.f, 0.f, __int_as_float(0));
  dstS[i] = N_;  // sentinel row of H/PDB (allocated, never read back)
}

// ---------------------------------------------------------------------------
// Per-node projections + H zeroing. LDS-tile streaming: block stages 16 node
// rows (hs|hv) via coalesced float4 loads; each wave computes 4 nodes with
// LDS-broadcast reads against register-held W1 rows.
//   PS[n,j]  = h_s[n]·W1[j,0:32] + h_v[n]·W1[j,64:96]
//   PDB[n,j] = h_s[n]·W1[j,32:64] + b1[j]
// ---------------------------------------------------------------------------
__global__ __launch_bounds__(256) void psd_kernel(
    const float* __restrict__ hout, const float* __restrict__ W1l,
    const float* __restrict__ b1l,
    float* __restrict__ PS, float* __restrict__ PDB, float* __restrict__ H, int N_) {
  __shared__ float wsh[99 * 64];
  __shared__ __align__(16) float hsh[TILE][64];
  int t = threadIdx.x;
  for (int i = t; i < 99 * 64; i += 256) wsh[i] = W1l[i];
  __syncthreads();
  int lane = t & 63, wib = t >> 6;
  float ws_[32], wd_[32], wv_[32];
#pragma unroll
  for (int k = 0; k < 32; ++k) {
    ws_[k] = wsh[lane * 99 + k];
    wd_[k] = wsh[lane * 99 + 32 + k];
    wv_[k] = wsh[lane * 99 + 64 + k];
  }
  float bb1 = b1l[lane];
  const int nTiles = (N_ + TILE - 1) / TILE;
  const float* hvbase = hout + (size_t)N_ * 32;
  // staging coords for this thread
  int tt = t & 127;
  int sn = tt >> 3;        // node slot 0..15
  int sc = tt & 7;         // float4 column 0..7 within 32 floats
  for (int tile = blockIdx.x; tile < nTiles; tile += gridDim.x) {
    int base = tile * TILE;
    {
      int n = base + sn;
      const float* src = (t < 128) ? (hout + (size_t)n * 32 + sc * 4)
                                   : (hvbase + (size_t)n * 32 + sc * 4);
      float4 v = (n < N_) ? *reinterpret_cast<const float4*>(src)
                          : make_float4(0.f, 0.f, 0.f, 0.f);
      *reinterpret_cast<float4*>(&hsh[sn][(t < 128 ? 0 : 32) + sc * 4]) = v;
    }
    __syncthreads();
#pragma unroll
    for (int q = 0; q < 4; ++q) {
      int r = wib + q * 4;
      int n = base + r;
      if (n < N_) {
        const float4* ha = reinterpret_cast<const float4*>(hsh[r]);
        float ps0 = 0.f, ps1 = 0.f, ps2 = 0.f, ps3 = 0.f, pd0 = 0.f, pd1 = 0.f;
#pragma unroll
        for (int k4 = 0; k4 < 8; ++k4) {
          float4 a = ha[k4];
          float4 v = ha[8 + k4];
          int k = k4 * 4;
          ps0 = fmaf(a.x, ws_[k], ps0);     pd0 = fmaf(a.x, wd_[k], pd0);
          ps1 = fmaf(a.y, ws_[k + 1], ps1); pd1 = fmaf(a.y, wd_[k + 1], pd1);
          ps2 = fmaf(a.z, ws_[k + 2], ps2); pd0 = fmaf(a.z, wd_[k + 2], pd0);
          ps3 = fmaf(a.w, ws_[k + 3], ps3); pd1 = fmaf(a.w, wd_[k + 3], pd1);
          ps0 = fmaf(v.x, wv_[k], ps0);
          ps1 = fmaf(v.y, wv_[k + 1], ps1);
          ps2 = fmaf(v.z, wv_[k + 2], ps2);
          ps3 = fmaf(v.w, wv_[k + 3], ps3);
        }
        PS[(size_t)n * 64 + lane] = (ps0 + ps1) + (ps2 + ps3);
        PDB[(size_t)n * 64 + lane] = (pd0 + pd1) + bb1;
        H[(size_t)n * 64 + lane] = 0.0f;
      }
    }
    __syncthreads();
  }
}

// ---------------------------------------------------------------------------
// Edge phase: one wave per 64-edge chunk of the dst-sorted edge array.
// Edge scalars arrive in ONE coalesced float4 + one int load; inner loop uses
// v_readlane (no loads for edge data). Segment flushes via wave-wide f32
// atomicAdd into H (~4 per chunk; boundaries from one ballot mask).
// ---------------------------------------------------------------------------
__global__ __launch_bounds__(256) void edge_kernel(
    const float* __restrict__ PS, const float* __restrict__ PDB,
    const float4* __restrict__ edata, const int* __restrict__ dstS,
    const float* __restrict__ W1l, float* __restrict__ H, int nchunk) {
  int lane = threadIdx.x & 63, wib = threadIdx.x >> 6;
  int chunk = blockIdx.x * WPB + wib;
  if (chunk >= nchunk) return;
  int base = chunk << 6;
  float wg0 = W1l[lane * 99 + 96];
  float wg1 = W1l[lane * 99 + 97];
  float wg2 = W1l[lane * 99 + 98];
  float4 ed = edata[base + lane];
  int dv = dstS[base + lane];
  int sv = __float_as_int(ed.w);
  int dprev = __shfl_up(dv, 1);
  unsigned long long bmask = __ballot(dv != dprev) & ~1ull;
  int dcur = rfl(dv);
  float pdj = PDB[(size_t)dcur * 64 + lane];
  float acc = 0.0f;
#pragma unroll
  for (int e = 0; e < 64; ++e) {
    if ((bmask >> e) & 1ull) {  // wave-uniform branch (~1 in 20)
      atomicAdd(H + (size_t)dcur * 64 + lane, acc);
      acc = 0.0f;
      dcur = __builtin_amdgcn_readlane(dv, e);
      pdj = PDB[(size_t)dcur * 64 + lane];
    }
    int se = __builtin_amdgcn_readlane(sv, e);
    float di = readlane_f(ed.x, e);
    float c2 = readlane_f(ed.y, e);
    float s2 = readlane_f(ed.z, e);
    float ps = PS[(size_t)se * 64 + lane];
    float pre = fmaf(wg0, di, fmaf(wg1, c2, fmaf(wg2, s2, ps + pdj)));
    acc += silu_f(pre);
  }
  atomicAdd(H + (size_t)dcur * 64 + lane, acc);
}

// ---------------------------------------------------------------------------
// Node update (planar h in d_out): h[n,:] += W2 . H[n,:] + deg(n)*b2
// LDS-tile streaming like psd: stage 16 H rows coalesced, wave computes 4.
// ---------------------------------------------------------------------------
__global__ __launch_bounds__(256) void out_kernel(
    float* __restrict__ hout, const float* __restrict__ H,
    const int* __restrict__ deg,
    const float* __restrict__ W2l, const float* __restrict__ b2l, int N_) {
  __shared__ float w2sh[64 * 65];
  __shared__ __align__(16) float Hsh[TILE][64];
  int t = threadIdx.x;
  for (int i = t; i < 64 * 64; i += 256) w2sh[(i >> 6) * 65 + (i & 63)] = W2l[i];
  __syncthreads();
  int lane = t & 63, wib = t >> 6;
  float w2[64];
#pragma unroll
  for (int k = 0; k < 64; ++k) w2[k] = w2sh[lane * 65 + k];
  float bb2 = b2l[lane];
  const int nTiles = (N_ + TILE - 1) / TILE;
  size_t plane = (size_t)(lane >> 5) * ((size_t)N_ * 32);
  int sn = t >> 4;   // node slot 0..15
  int sc = t & 15;   // float4 column 0..15 within 64 floats
  for (int tile = blockIdx.x; tile < nTiles; tile += gridDim.x) {
    int base = tile * TILE;
    {
      int n = base + sn;
      float4 v = (n < N_) ? *reinterpret_cast<const float4*>(H + (size_t)n * 64 + sc * 4)
                          : make_float4(0.f, 0.f, 0.f, 0.f);
      *reinterpret_cast<float4*>(&Hsh[sn][sc * 4]) = v;
    }
    __syncthreads();
#pragma unroll
    for (int q = 0; q < 4; ++q) {
      int r = wib + q * 4;
      int n = base + r;
      if (n < N_) {
        const float4* hm = reinterpret_cast<const float4*>(Hsh[r]);
        float o0 = 0.f, o1 = 0.f;
#pragma unroll
        for (int k4 = 0; k4 < 16; k4 += 2) {
          float4 m0 = hm[k4];
          float4 m1 = hm[k4 + 1];
          o0 = fmaf(m0.x, w2[k4 * 4 + 0], o0);
          o0 = fmaf(m0.y, w2[k4 * 4 + 1], o0);
          o0 = fmaf(m0.z, w2[k4 * 4 + 2], o0);
          o0 = fmaf(m0.w, w2[k4 * 4 + 3], o0);
          o1 = fmaf(m1.x, w2[k4 * 4 + 4], o1);
          o1 = fmaf(m1.y, w2[k4 * 4 + 5], o1);
          o1 = fmaf(m1.z, w2[k4 * 4 + 6], o1);
          o1 = fmaf(m1.w, w2[k4 * 4 + 7], o1);
        }
        float degf = (float)deg[n];
        size_t idx = plane + (size_t)n * 32 + (lane & 31);
        hout[idx] += (o0 + o1) + degf * bb2;
      }
    }
    __syncthreads();
  }
}

extern "C" void kernel_launch(void* const* d_in, const int* in_sizes, int n_in,
                              void* d_out, int out_size, void* d_ws, size_t ws_size,
                              hipStream_t stream) {
  const float* pos      = (const float*)d_in[0];
  const float* redshift = (const float*)d_in[1];
  const float* shapes   = (const float*)d_in[2];
  const int*   ei       = (const int*)d_in[3];
  const float* enc_s_w  = (const float*)d_in[4];
  const float* enc_s_b  = (const float*)d_in[5];
  const float* enc_v_w  = (const float*)d_in[6];
  const float* W1       = (const float*)d_in[7];
  const float* b1       = (const float*)d_in[8];
  const float* W2       = (const float*)d_in[9];
  const float* b2       = (const float*)d_in[10];

  const int N_ = in_sizes[1];      // 50000
  const int E_ = in_sizes[3] / 2;  // 1000000
  const int nchunk = (E_ + 63) / 64;
  const int padE = nchunk * 64;

  // Workspace (~59 MB): edata first (16B alignment from d_ws base)
  float4* edata = (float4*)d_ws;                       // padE
  float* PS     = (float*)(edata + padE);              // N*64
  float* PDB    = PS + (size_t)N_ * 64;                // (N+1)*64 (pad row)
  float* H      = PDB + (size_t)(N_ + 1) * 64;         // (N+1)*64 (pad row)
  int* dstS     = (int*)(H + (size_t)(N_ + 1) * 64);   // padE (perm, then dst)
  int* rowptr   = dstS + padE;                         // N+1
  int* deg      = rowptr + (N_ + 1);                   // N
  int* cursor   = deg + N_;                            // N (adjacent to deg)
  int* bsum     = cursor + N_;                         // 1024

  float* hout = (float*)d_out;  // planar h lives in d_out

  encode_kernel<<<dim3((N_ * 32 + 255) / 256), dim3(256), 0, stream>>>(
      redshift, shapes, enc_s_w, enc_s_b, enc_v_w, hout, N_);

  // CSR build + layer-invariant geometry (once)
  zero_kernel<<<dim3((2 * N_ + 255) / 256), dim3(256), 0, stream>>>(deg, 2 * N_);
  deg_kernel<<<dim3((E_ + 255) / 256), dim3(256), 0, stream>>>(ei, deg, E_);
  const int nbA = (N_ + 1023) / 1024;
  scanA_kernel<<<dim3(nbA), dim3(1024), 0, stream>>>(deg, rowptr, bsum, N_);
  scanB_kernel<<<dim3(1), dim3(1024), 0, stream>>>(bsum, nbA);
  scanC_kernel<<<dim3((N_ + 255) / 256), dim3(256), 0, stream>>>(rowptr, bsum, N_);
  scatter1_kernel<<<dim3((E_ + 255) / 256), dim3(256), 0, stream>>>(
      ei, rowptr, cursor, dstS, E_);
  scatter2_kernel<<<dim3((E_ + 255) / 256), dim3(256), 0, stream>>>(
      ei, pos, dstS, edata, E_);
  if (padE > E_)
    pad_kernel<<<dim3(1), dim3(padE - E_), 0, stream>>>(edata, dstS, E_, N_);

  const int edgeBlocks = (nchunk + WPB - 1) / WPB;
  for (int l = 0; l < 3; ++l) {
    const float* W1l = W1 + (size_t)l * 64 * 99;
    const float* b1l = b1 + (size_t)l * 64;
    const float* W2l = W2 + (size_t)l * 64 * 64;
    const float* b2l = b2 + (size_t)l * 64;
    psd_kernel<<<dim3(1024), dim3(256), 0, stream>>>(hout, W1l, b1l, PS, PDB, H, N_);
    edge_kernel<<<dim3(edgeBlocks), dim3(256), 0, stream>>>(
        PS, PDB, edata, dstS, W1l, H, nchunk);
    out_kernel<<<dim3(1024), dim3(256), 0, stream>>>(hout, H, deg, W2l, b2l, N_);
  }
}

// Round 6
// 408.805 us; speedup vs baseline: 5.6549x; 1.0878x over previous
//
#include <hip/hip_runtime.h>
#include <hip/hip_bf16.h>

#define WPB 4   // waves per block (256 threads)
#define TILE 16 // node rows staged per block iteration

typedef unsigned short ushort_t;
typedef unsigned int uint_t;

__device__ __forceinline__ float silu_f(float x) {
  return x * __builtin_amdgcn_rcpf(1.0f + __expf(-x));
}
__device__ __forceinline__ int rfl(int x) { return __builtin_amdgcn_readfirstlane(x); }
__device__ __forceinline__ float readlane_f(float v, int l) {
  return __int_as_float(__builtin_amdgcn_readlane(__float_as_int(v), l));
}
// f32 -> bf16 with round-to-nearest-even
__device__ __forceinline__ ushort_t f2bf(float f) {
  uint_t u = __float_as_uint(f);
  u += 0x7FFFu + ((u >> 16) & 1u);
  return (ushort_t)(u >> 16);
}
__device__ __forceinline__ float bf2f(ushort_t b) {
  return __uint_as_float(((uint_t)b) << 16);
}

// ---------------------------------------------------------------------------
// Encode directly into d_out (planar): out[0..N*32) = h_s, out[N*32..) = h_v
// ---------------------------------------------------------------------------
__global__ void encode_kernel(const float* __restrict__ redshift,
                              const float* __restrict__ shapes,
                              const float* __restrict__ enc_s_w,
                              const float* __restrict__ enc_s_b,
                              const float* __restrict__ enc_v_w,
                              float* __restrict__ hout, int N_) {
  int tid = blockIdx.x * blockDim.x + threadIdx.x;
  int n = tid >> 5;
  int j = tid & 31;
  if (n >= N_) return;
  float r = redshift[n];
  float hs = fmaxf(fmaf(r, enc_s_w[j], enc_s_b[j]), 0.0f);
  float x0 = shapes[n * 2 + 0];
  float x1 = shapes[n * 2 + 1];
  float hv = fmaf(x0, enc_v_w[j * 2 + 0], x1 * enc_v_w[j * 2 + 1]);
  hout[(size_t)n * 32 + j] = hs;
  hout[(size_t)N_ * 32 + (size_t)n * 32 + j] = hv;
}

__global__ void zero_kernel(int* __restrict__ p, int n) {
  int i = blockIdx.x * blockDim.x + threadIdx.x;
  if (i < n) p[i] = 0;
}

// ---------------------------------------------------------------------------
// CSR build (once): degree, hierarchical scan, ONE fused scatter pass
// (geometry computed in-scatter; pos is L2-resident so random reads are cheap;
// the scattered line-touch toll is paid exactly once).
// ---------------------------------------------------------------------------
__global__ void deg_kernel(const int* __restrict__ ei, int* __restrict__ deg, int E_) {
  int e = blockIdx.x * blockDim.x + threadIdx.x;
  if (e < E_) atomicAdd(&deg[ei[E_ + e]], 1);
}

__global__ __launch_bounds__(1024) void scanA_kernel(const int* __restrict__ deg,
                                                     int* __restrict__ rowptr,
                                                     int* __restrict__ bsum, int n) {
  __shared__ int wsum[16];
  int t = threadIdx.x, lane = t & 63, wid = t >> 6;
  int i = blockIdx.x * 1024 + t;
  int v = (i < n) ? deg[i] : 0;
  int x = v;
#pragma unroll
  for (int off = 1; off < 64; off <<= 1) {
    int y = __shfl_up(x, off);
    if (lane >= off) x += y;
  }
  if (lane == 63) wsum[wid] = x;
  __syncthreads();
  if (t == 0) {
    int run = 0;
#pragma unroll
    for (int w = 0; w < 16; ++w) { int s = wsum[w]; wsum[w] = run; run += s; }
  }
  __syncthreads();
  int inc = x + wsum[wid];
  if (i < n) rowptr[i + 1] = inc;  // inclusive within block
  if (t == 1023) bsum[blockIdx.x] = inc;
}

__global__ __launch_bounds__(1024) void scanB_kernel(int* __restrict__ bsum, int nb) {
  __shared__ int wsum[16];
  int t = threadIdx.x, lane = t & 63, wid = t >> 6;
  int v = (t < nb) ? bsum[t] : 0;
  int x = v;
#pragma unroll
  for (int off = 1; off < 64; off <<= 1) {
    int y = __shfl_up(x, off);
    if (lane >= off) x += y;
  }
  if (lane == 63) wsum[wid] = x;
  __syncthreads();
  if (t == 0) {
    int run = 0;
#pragma unroll
    for (int w = 0; w < 16; ++w) { int s = wsum[w]; wsum[w] = run; run += s; }
  }
  __syncthreads();
  if (t < nb) bsum[t] = x - v + wsum[wid];  // exclusive
}

__global__ void scanC_kernel(int* __restrict__ rowptr, const int* __restrict__ bsum, int n) {
  int i = blockIdx.x * blockDim.x + threadIdx.x;
  if (i == 0) rowptr[0] = 0;
  if (i < n) rowptr[i + 1] += bsum[i >> 10];
}

// Fused scatter: edata = (dist, cos2phi, sin2phi, src_bits), dstS = dst.
// Pad tail (slots E_..padE) folded into the same grid.
__global__ void scatter_kernel(const int* __restrict__ ei, const float* __restrict__ pos,
                               const int* __restrict__ rowptr, int* __restrict__ cursor,
                               float4* __restrict__ edata, int* __restrict__ dstS,
                               int E_, int padE, int N_) {
  int e = blockIdx.x * blockDim.x + threadIdx.x;
  if (e >= padE) return;
  if (e >= E_) {  // sentinel slots
    edata[e] = make_float4(0.f, 0.f, 0.f, __int_as_float(0));
    dstS[e] = N_;
    return;
  }
  int s = ei[e];
  int d = ei[E_ + e];
  int idx = rowptr[d] + atomicAdd(&cursor[d], 1);
  float dx = pos[s * 2 + 0] - pos[d * 2 + 0];
  float dy = pos[s * 2 + 1] - pos[d * 2 + 1];
  float r2 = fmaf(dx, dx, dy * dy);
  float dist = sqrtf(r2) + 1e-6f;
  float c2 = 1.0f, s2 = 0.0f;
  if (r2 > 0.0f) {
    float inv = 1.0f / r2;
    c2 = (dx * dx - dy * dy) * inv;
    s2 = 2.0f * dx * dy * inv;
  }
  edata[idx] = make_float4(dist, c2, s2, __int_as_float(s));
  dstS[idx] = d;
}

// ---------------------------------------------------------------------------
// Per-node projections + H zeroing. LDS-tile streaming. PS stored as bf16
// (halves the edge kernel's dominant gather traffic).
//   PS[n,j]  = h_s[n]·W1[j,0:32] + h_v[n]·W1[j,64:96]   (bf16)
//   PDB[n,j] = h_s[n]·W1[j,32:64] + b1[j]               (f32)
// ---------------------------------------------------------------------------
__global__ __launch_bounds__(256) void psd_kernel(
    const float* __restrict__ hout, const float* __restrict__ W1l,
    const float* __restrict__ b1l,
    ushort_t* __restrict__ PSh, float* __restrict__ PDB, float* __restrict__ H, int N_) {
  __shared__ float wsh[99 * 64];
  __shared__ __align__(16) float hsh[TILE][64];
  int t = threadIdx.x;
  for (int i = t; i < 99 * 64; i += 256) wsh[i] = W1l[i];
  __syncthreads();
  int lane = t & 63, wib = t >> 6;
  float ws_[32], wd_[32], wv_[32];
#pragma unroll
  for (int k = 0; k < 32; ++k) {
    ws_[k] = wsh[lane * 99 + k];
    wd_[k] = wsh[lane * 99 + 32 + k];
    wv_[k] = wsh[lane * 99 + 64 + k];
  }
  float bb1 = b1l[lane];
  const int nTiles = (N_ + TILE - 1) / TILE;
  const float* hvbase = hout + (size_t)N_ * 32;
  int tt = t & 127;
  int sn = tt >> 3;        // node slot 0..15
  int sc = tt & 7;         // float4 column 0..7 within 32 floats
  for (int tile = blockIdx.x; tile < nTiles; tile += gridDim.x) {
    int base = tile * TILE;
    {
      int n = base + sn;
      const float* src = (t < 128) ? (hout + (size_t)n * 32 + sc * 4)
                                   : (hvbase + (size_t)n * 32 + sc * 4);
      float4 v = (n < N_) ? *reinterpret_cast<const float4*>(src)
                          : make_float4(0.f, 0.f, 0.f, 0.f);
      *reinterpret_cast<float4*>(&hsh[sn][(t < 128 ? 0 : 32) + sc * 4]) = v;
    }
    __syncthreads();
#pragma unroll
    for (int q = 0; q < 4; ++q) {
      int r = wib + q * 4;
      int n = base + r;
      if (n < N_) {
        const float4* ha = reinterpret_cast<const float4*>(hsh[r]);
        float ps0 = 0.f, ps1 = 0.f, ps2 = 0.f, ps3 = 0.f, pd0 = 0.f, pd1 = 0.f;
#pragma unroll
        for (int k4 = 0; k4 < 8; ++k4) {
          float4 a = ha[k4];
          float4 v = ha[8 + k4];
          int k = k4 * 4;
          ps0 = fmaf(a.x, ws_[k], ps0);     pd0 = fmaf(a.x, wd_[k], pd0);
          ps1 = fmaf(a.y, ws_[k + 1], ps1); pd1 = fmaf(a.y, wd_[k + 1], pd1);
          ps2 = fmaf(a.z, ws_[k + 2], ps2); pd0 = fmaf(a.z, wd_[k + 2], pd0);
          ps3 = fmaf(a.w, ws_[k + 3], ps3); pd1 = fmaf(a.w, wd_[k + 3], pd1);
          ps0 = fmaf(v.x, wv_[k], ps0);
          ps1 = fmaf(v.y, wv_[k + 1], ps1);
          ps2 = fmaf(v.z, wv_[k + 2], ps2);
          ps3 = fmaf(v.w, wv_[k + 3], ps3);
        }
        PSh[(size_t)n * 64 + lane] = f2bf((ps0 + ps1) + (ps2 + ps3));
        PDB[(size_t)n * 64 + lane] = (pd0 + pd1) + bb1;
        H[(size_t)n * 64 + lane] = 0.0f;
      }
    }
    __syncthreads();
  }
}

// ---------------------------------------------------------------------------
// Edge phase: one wave per 64-edge chunk of the dst-sorted edge array.
// Edge scalars arrive in ONE coalesced float4 + one int load; inner loop uses
// v_readlane (no loads for edge data). PS gathered as bf16 (128B/wave/edge).
// Segment flushes via wave-wide f32 atomicAdd into H (~4 per chunk).
// ---------------------------------------------------------------------------
__global__ __launch_bounds__(256) void edge_kernel(
    const ushort_t* __restrict__ PSh, const float* __restrict__ PDB,
    const float4* __restrict__ edata, const int* __restrict__ dstS,
    const float* __restrict__ W1l, float* __restrict__ H, int nchunk) {
  int lane = threadIdx.x & 63, wib = threadIdx.x >> 6;
  int chunk = blockIdx.x * WPB + wib;
  if (chunk >= nchunk) return;
  int base = chunk << 6;
  float wg0 = W1l[lane * 99 + 96];
  float wg1 = W1l[lane * 99 + 97];
  float wg2 = W1l[lane * 99 + 98];
  float4 ed = edata[base + lane];
  int dv = dstS[base + lane];
  int sv = __float_as_int(ed.w);
  int dprev = __shfl_up(dv, 1);
  unsigned long long bmask = __ballot(dv != dprev) & ~1ull;
  int dcur = rfl(dv);
  float pdj = PDB[(size_t)dcur * 64 + lane];
  float acc = 0.0f;
#pragma unroll
  for (int e = 0; e < 64; ++e) {
    if ((bmask >> e) & 1ull) {  // wave-uniform branch (~1 in 20)
      atomicAdd(H + (size_t)dcur * 64 + lane, acc);
      acc = 0.0f;
      dcur = __builtin_amdgcn_readlane(dv, e);
      pdj = PDB[(size_t)dcur * 64 + lane];
    }
    int se = __builtin_amdgcn_readlane(sv, e);
    float di = readlane_f(ed.x, e);
    float c2 = readlane_f(ed.y, e);
    float s2 = readlane_f(ed.z, e);
    float ps = bf2f(PSh[(size_t)se * 64 + lane]);
    float pre = fmaf(wg0, di, fmaf(wg1, c2, fmaf(wg2, s2, ps + pdj)));
    acc += silu_f(pre);
  }
  atomicAdd(H + (size_t)dcur * 64 + lane, acc);
}

// ---------------------------------------------------------------------------
// Node update (planar h in d_out): h[n,:] += W2 . H[n,:] + deg(n)*b2
// LDS-tile streaming: stage 16 H rows coalesced, wave computes 4.
// ---------------------------------------------------------------------------
__global__ __launch_bounds__(256) void out_kernel(
    float* __restrict__ hout, const float* __restrict__ H,
    const int* __restrict__ deg,
    const float* __restrict__ W2l, const float* __restrict__ b2l, int N_) {
  __shared__ float w2sh[64 * 65];
  __shared__ __align__(16) float Hsh[TILE][64];
  int t = threadIdx.x;
  for (int i = t; i < 64 * 64; i += 256) w2sh[(i >> 6) * 65 + (i & 63)] = W2l[i];
  __syncthreads();
  int lane = t & 63, wib = t >> 6;
  float w2[64];
#pragma unroll
  for (int k = 0; k < 64; ++k) w2[k] = w2sh[lane * 65 + k];
  float bb2 = b2l[lane];
  const int nTiles = (N_ + TILE - 1) / TILE;
  size_t plane = (size_t)(lane >> 5) * ((size_t)N_ * 32);
  int sn = t >> 4;   // node slot 0..15
  int sc = t & 15;   // float4 column 0..15 within 64 floats
  for (int tile = blockIdx.x; tile < nTiles; tile += gridDim.x) {
    int base = tile * TILE;
    {
      int n = base + sn;
      float4 v = (n < N_) ? *reinterpret_cast<const float4*>(H + (size_t)n * 64 + sc * 4)
                          : make_float4(0.f, 0.f, 0.f, 0.f);
      *reinterpret_cast<float4*>(&Hsh[sn][sc * 4]) = v;
    }
    __syncthreads();
#pragma unroll
    for (int q = 0; q < 4; ++q) {
      int r = wib + q * 4;
      int n = base + r;
      if (n < N_) {
        const float4* hm = reinterpret_cast<const float4*>(Hsh[r]);
        float o0 = 0.f, o1 = 0.f;
#pragma unroll
        for (int k4 = 0; k4 < 16; k4 += 2) {
          float4 m0 = hm[k4];
          float4 m1 = hm[k4 + 1];
          o0 = fmaf(m0.x, w2[k4 * 4 + 0], o0);
          o0 = fmaf(m0.y, w2[k4 * 4 + 1], o0);
          o0 = fmaf(m0.z, w2[k4 * 4 + 2], o0);
          o0 = fmaf(m0.w, w2[k4 * 4 + 3], o0);
          o1 = fmaf(m1.x, w2[k4 * 4 + 4], o1);
          o1 = fmaf(m1.y, w2[k4 * 4 + 5], o1);
          o1 = fmaf(m1.z, w2[k4 * 4 + 6], o1);
          o1 = fmaf(m1.w, w2[k4 * 4 + 7], o1);
        }
        float degf = (float)deg[n];
        size_t idx = plane + (size_t)n * 32 + (lane & 31);
        hout[idx] += (o0 + o1) + degf * bb2;
      }
    }
    __syncthreads();
  }
}

extern "C" void kernel_launch(void* const* d_in, const int* in_sizes, int n_in,
                              void* d_out, int out_size, void* d_ws, size_t ws_size,
                              hipStream_t stream) {
  const float* pos      = (const float*)d_in[0];
  const float* redshift = (const float*)d_in[1];
  const float* shapes   = (const float*)d_in[2];
  const int*   ei       = (const int*)d_in[3];
  const float* enc_s_w  = (const float*)d_in[4];
  const float* enc_s_b  = (const float*)d_in[5];
  const float* enc_v_w  = (const float*)d_in[6];
  const float* W1       = (const float*)d_in[7];
  const float* b1       = (const float*)d_in[8];
  const float* W2       = (const float*)d_in[9];
  const float* b2       = (const float*)d_in[10];

  const int N_ = in_sizes[1];      // 50000
  const int E_ = in_sizes[3] / 2;  // 1000000
  const int nchunk = (E_ + 63) / 64;
  const int padE = nchunk * 64;

  // Workspace (~53 MB): edata first (16B alignment from d_ws base)
  float4*   edata = (float4*)d_ws;                         // padE
  float*    PDB   = (float*)(edata + padE);                // (N+1)*64 (pad row)
  float*    H     = PDB + (size_t)(N_ + 1) * 64;           // (N+1)*64 (pad row)
  ushort_t* PSh   = (ushort_t*)(H + (size_t)(N_ + 1) * 64);// N*64 bf16
  int* dstS   = (int*)(PSh + (size_t)N_ * 64);             // padE
  int* rowptr = dstS + padE;                               // N+1
  int* deg    = rowptr + (N_ + 1);                         // N
  int* cursor = deg + N_;                                  // N (adjacent to deg)
  int* bsum   = cursor + N_;                               // 1024

  float* hout = (float*)d_out;  // planar h lives in d_out

  encode_kernel<<<dim3((N_ * 32 + 255) / 256), dim3(256), 0, stream>>>(
      redshift, shapes, enc_s_w, enc_s_b, enc_v_w, hout, N_);

  // CSR build + layer-invariant geometry (once)
  zero_kernel<<<dim3((2 * N_ + 255) / 256), dim3(256), 0, stream>>>(deg, 2 * N_);
  deg_kernel<<<dim3((E_ + 255) / 256), dim3(256), 0, stream>>>(ei, deg, E_);
  const int nbA = (N_ + 1023) / 1024;
  scanA_kernel<<<dim3(nbA), dim3(1024), 0, stream>>>(deg, rowptr, bsum, N_);
  scanB_kernel<<<dim3(1), dim3(1024), 0, stream>>>(bsum, nbA);
  scanC_kernel<<<dim3((N_ + 255) / 256), dim3(256), 0, stream>>>(rowptr, bsum, N_);
  scatter_kernel<<<dim3((padE + 255) / 256), dim3(256), 0, stream>>>(
      ei, pos, rowptr, cursor, edata, dstS, E_, padE, N_);

  const int edgeBlocks = (nchunk + WPB - 1) / WPB;
  for (int l = 0; l < 3; ++l) {
    const float* W1l = W1 + (size_t)l * 64 * 99;
    const float* b1l = b1 + (size_t)l * 64;
    const float* W2l = W2 + (size_t)l * 64 * 64;
    const float* b2l = b2 + (size_t)l * 64;
    psd_kernel<<<dim3(1024), dim3(256), 0, stream>>>(hout, W1l, b1l, PSh, PDB, H, N_);
    edge_kernel<<<dim3(edgeBlocks), dim3(256), 0, stream>>>(
        PSh, PDB, edata, dstS, W1l, H, nchunk);
    out_kernel<<<dim3(1024), dim3(256), 0, stream>>>(hout, H, deg, W2l, b2l, N_);
  }
}

// Round 7
// 401.656 us; speedup vs baseline: 5.7556x; 1.0178x over previous
//
#include <hip/hip_runtime.h>
#include <hip/hip_bf16.h>

#define WPB 4   // waves per block (256 threads)
#define TILE 16 // node rows staged per block iteration

typedef unsigned short ushort_t;
typedef unsigned int uint_t;

__device__ __forceinline__ float silu_f(float x) {
  return x * __builtin_amdgcn_rcpf(1.0f + __expf(-x));
}
__device__ __forceinline__ int rfl(int x) { return __builtin_amdgcn_readfirstlane(x); }
__device__ __forceinline__ float readlane_f(float v, int l) {
  return __int_as_float(__builtin_amdgcn_readlane(__float_as_int(v), l));
}
// f32 -> bf16 round-to-nearest-even
__device__ __forceinline__ ushort_t f2bf(float f) {
  uint_t u = __float_as_uint(f);
  u += 0x7FFFu + ((u >> 16) & 1u);
  return (ushort_t)(u >> 16);
}
__device__ __forceinline__ float bf2f(ushort_t b) {
  return __uint_as_float(((uint_t)b) << 16);
}

// ---------------------------------------------------------------------------
// Encode directly into d_out (planar): out[0..N*32) = h_s, out[N*32..) = h_v
// ---------------------------------------------------------------------------
__global__ void encode_kernel(const float* __restrict__ redshift,
                              const float* __restrict__ shapes,
                              const float* __restrict__ enc_s_w,
                              const float* __restrict__ enc_s_b,
                              const float* __restrict__ enc_v_w,
                              float* __restrict__ hout, int N_) {
  int tid = blockIdx.x * blockDim.x + threadIdx.x;
  int n = tid >> 5;
  int j = tid & 31;
  if (n >= N_) return;
  float r = redshift[n];
  float hs = fmaxf(fmaf(r, enc_s_w[j], enc_s_b[j]), 0.0f);
  float x0 = shapes[n * 2 + 0];
  float x1 = shapes[n * 2 + 1];
  float hv = fmaf(x0, enc_v_w[j * 2 + 0], x1 * enc_v_w[j * 2 + 1]);
  hout[(size_t)n * 32 + j] = hs;
  hout[(size_t)N_ * 32 + (size_t)n * 32 + j] = hv;
}

__global__ void zero_kernel(int* __restrict__ p, int n) {
  int i = blockIdx.x * blockDim.x + threadIdx.x;
  if (i < n) p[i] = 0;
}

// ---------------------------------------------------------------------------
// CSR build (once): degree, hierarchical scan, ONE fused scatter pass.
// ---------------------------------------------------------------------------
__global__ void deg_kernel(const int* __restrict__ ei, int* __restrict__ deg, int E_) {
  int e = blockIdx.x * blockDim.x + threadIdx.x;
  if (e < E_) atomicAdd(&deg[ei[E_ + e]], 1);
}

__global__ __launch_bounds__(1024) void scanA_kernel(const int* __restrict__ deg,
                                                     int* __restrict__ rowptr,
                                                     int* __restrict__ bsum, int n) {
  __shared__ int wsum[16];
  int t = threadIdx.x, lane = t & 63, wid = t >> 6;
  int i = blockIdx.x * 1024 + t;
  int v = (i < n) ? deg[i] : 0;
  int x = v;
#pragma unroll
  for (int off = 1; off < 64; off <<= 1) {
    int y = __shfl_up(x, off);
    if (lane >= off) x += y;
  }
  if (lane == 63) wsum[wid] = x;
  __syncthreads();
  if (t == 0) {
    int run = 0;
#pragma unroll
    for (int w = 0; w < 16; ++w) { int s = wsum[w]; wsum[w] = run; run += s; }
  }
  __syncthreads();
  int inc = x + wsum[wid];
  if (i < n) rowptr[i + 1] = inc;  // inclusive within block
  if (t == 1023) bsum[blockIdx.x] = inc;
}

__global__ __launch_bounds__(1024) void scanB_kernel(int* __restrict__ bsum, int nb) {
  __shared__ int wsum[16];
  int t = threadIdx.x, lane = t & 63, wid = t >> 6;
  int v = (t < nb) ? bsum[t] : 0;
  int x = v;
#pragma unroll
  for (int off = 1; off < 64; off <<= 1) {
    int y = __shfl_up(x, off);
    if (lane >= off) x += y;
  }
  if (lane == 63) wsum[wid] = x;
  __syncthreads();
  if (t == 0) {
    int run = 0;
#pragma unroll
    for (int w = 0; w < 16; ++w) { int s = wsum[w]; wsum[w] = run; run += s; }
  }
  __syncthreads();
  if (t < nb) bsum[t] = x - v + wsum[wid];  // exclusive
}

__global__ void scanC_kernel(int* __restrict__ rowptr, const int* __restrict__ bsum, int n) {
  int i = blockIdx.x * blockDim.x + threadIdx.x;
  if (i == 0) rowptr[0] = 0;
  if (i < n) rowptr[i + 1] += bsum[i >> 10];
}

// Fused scatter: edata = (dist, cos2phi, sin2phi, src_bits), dstS = dst.
__global__ void scatter_kernel(const int* __restrict__ ei, const float* __restrict__ pos,
                               const int* __restrict__ rowptr, int* __restrict__ cursor,
                               float4* __restrict__ edata, int* __restrict__ dstS,
                               int E_, int padE, int N_) {
  int e = blockIdx.x * blockDim.x + threadIdx.x;
  if (e >= padE) return;
  if (e >= E_) {  // sentinel slots
    edata[e] = make_float4(0.f, 0.f, 0.f, __int_as_float(0));
    dstS[e] = N_;
    return;
  }
  int s = ei[e];
  int d = ei[E_ + e];
  int idx = rowptr[d] + atomicAdd(&cursor[d], 1);
  float dx = pos[s * 2 + 0] - pos[d * 2 + 0];
  float dy = pos[s * 2 + 1] - pos[d * 2 + 1];
  float r2 = fmaf(dx, dx, dy * dy);
  float dist = sqrtf(r2) + 1e-6f;
  float c2 = 1.0f, s2 = 0.0f;
  if (r2 > 0.0f) {
    float inv = 1.0f / r2;
    c2 = (dx * dx - dy * dy) * inv;
    s2 = 2.0f * dx * dy * inv;
  }
  edata[idx] = make_float4(dist, c2, s2, __int_as_float(s));
  dstS[idx] = d;
}

// ---------------------------------------------------------------------------
// Standalone projections (layer 0 only) + H zeroing.
//   PS[n,j]  = h_s[n]·W1[j,0:32] + h_v[n]·W1[j,64:96]   (bf16)
//   PDB[n,j] = h_s[n]·W1[j,32:64] + b1[j]               (bf16)
// ---------------------------------------------------------------------------
__global__ __launch_bounds__(256) void psd_kernel(
    const float* __restrict__ hout, const float* __restrict__ W1l,
    const float* __restrict__ b1l,
    ushort_t* __restrict__ PSh, ushort_t* __restrict__ PDBh,
    float* __restrict__ H, int N_) {
  __shared__ float wsh[99 * 64];
  __shared__ __align__(16) float hsh[TILE][64];
  int t = threadIdx.x;
  for (int i = t; i < 99 * 64; i += 256) wsh[i] = W1l[i];
  __syncthreads();
  int lane = t & 63, wib = t >> 6;
  float ws_[32], wd_[32], wv_[32];
#pragma unroll
  for (int k = 0; k < 32; ++k) {
    ws_[k] = wsh[lane * 99 + k];
    wd_[k] = wsh[lane * 99 + 32 + k];
    wv_[k] = wsh[lane * 99 + 64 + k];
  }
  float bb1 = b1l[lane];
  const int nTiles = (N_ + TILE - 1) / TILE;
  const float* hvbase = hout + (size_t)N_ * 32;
  int tt = t & 127;
  int sn = tt >> 3;        // node slot 0..15
  int sc = tt & 7;         // float4 column 0..7 within 32 floats
  for (int tile = blockIdx.x; tile < nTiles; tile += gridDim.x) {
    int base = tile * TILE;
    {
      int n = base + sn;
      const float* src = (t < 128) ? (hout + (size_t)n * 32 + sc * 4)
                                   : (hvbase + (size_t)n * 32 + sc * 4);
      float4 v = (n < N_) ? *reinterpret_cast<const float4*>(src)
                          : make_float4(0.f, 0.f, 0.f, 0.f);
      *reinterpret_cast<float4*>(&hsh[sn][(t < 128 ? 0 : 32) + sc * 4]) = v;
    }
    __syncthreads();
#pragma unroll
    for (int q = 0; q < 4; ++q) {
      int r = wib + q * 4;
      int n = base + r;
      if (n < N_) {
        const float4* ha = reinterpret_cast<const float4*>(hsh[r]);
        float ps0 = 0.f, ps1 = 0.f, ps2 = 0.f, ps3 = 0.f, pd0 = 0.f, pd1 = 0.f;
#pragma unroll
        for (int k4 = 0; k4 < 8; ++k4) {
          float4 a = ha[k4];
          float4 v = ha[8 + k4];
          int k = k4 * 4;
          ps0 = fmaf(a.x, ws_[k], ps0);     pd0 = fmaf(a.x, wd_[k], pd0);
          ps1 = fmaf(a.y, ws_[k + 1], ps1); pd1 = fmaf(a.y, wd_[k + 1], pd1);
          ps2 = fmaf(a.z, ws_[k + 2], ps2); pd0 = fmaf(a.z, wd_[k + 2], pd0);
          ps3 = fmaf(a.w, ws_[k + 3], ps3); pd1 = fmaf(a.w, wd_[k + 3], pd1);
          ps0 = fmaf(v.x, wv_[k], ps0);
          ps1 = fmaf(v.y, wv_[k + 1], ps1);
          ps2 = fmaf(v.z, wv_[k + 2], ps2);
          ps3 = fmaf(v.w, wv_[k + 3], ps3);
        }
        PSh[(size_t)n * 64 + lane] = f2bf((ps0 + ps1) + (ps2 + ps3));
        PDBh[(size_t)n * 64 + lane] = f2bf((pd0 + pd1) + bb1);
        H[(size_t)n * 64 + lane] = 0.0f;
      }
    }
    __syncthreads();
  }
}

// ---------------------------------------------------------------------------
// Edge phase: one wave per 64-edge chunk of the dst-sorted edge array.
// Segment-boundary PDB loads are prefetched one full segment ahead (all
// boundaries known from one ballot at chunk start) -> no dependent-load stall
// in the inner loop. Dual accumulators break the serial silu/add chain.
// ---------------------------------------------------------------------------
__global__ __launch_bounds__(256) void edge_kernel(
    const ushort_t* __restrict__ PSh, const ushort_t* __restrict__ PDBh,
    const float4* __restrict__ edata, const int* __restrict__ dstS,
    const float* __restrict__ W1l, float* __restrict__ H, int nchunk) {
  int lane = threadIdx.x & 63, wib = threadIdx.x >> 6;
  int chunk = blockIdx.x * WPB + wib;
  if (chunk >= nchunk) return;
  int base = chunk << 6;
  float wg0 = W1l[lane * 99 + 96];
  float wg1 = W1l[lane * 99 + 97];
  float wg2 = W1l[lane * 99 + 98];
  float4 ed = edata[base + lane];
  int dv = dstS[base + lane];
  int sv = __float_as_int(ed.w);
  int dprev = __shfl_up(dv, 1);
  unsigned long long bmask = __ballot(dv != dprev) & ~1ull;
  int dcur = rfl(dv);
  float pdj = bf2f(PDBh[(size_t)dcur * 64 + lane]);
  // prefetch first boundary's pdj one segment ahead
  int bnext = bmask ? (int)__builtin_ctzll(bmask) : 64;
  int dnext = (bnext < 64) ? __builtin_amdgcn_readlane(dv, bnext) : dcur;
  float pdj_next = bf2f(PDBh[(size_t)dnext * 64 + lane]);
  float acc0 = 0.0f, acc1 = 0.0f;
#pragma unroll
  for (int e = 0; e < 64; ++e) {
    if (e == bnext) {  // wave-uniform scalar compare
      atomicAdd(H + (size_t)dcur * 64 + lane, acc0 + acc1);
      acc0 = acc1 = 0.0f;
      dcur = dnext;
      pdj = pdj_next;  // already in flight for a whole segment
      bmask &= bmask - 1;
      bnext = bmask ? (int)__builtin_ctzll(bmask) : 64;
      dnext = (bnext < 64) ? __builtin_amdgcn_readlane(dv, bnext) : dcur;
      pdj_next = bf2f(PDBh[(size_t)dnext * 64 + lane]);
    }
    int se = __builtin_amdgcn_readlane(sv, e);
    float di = readlane_f(ed.x, e);
    float c2 = readlane_f(ed.y, e);
    float s2 = readlane_f(ed.z, e);
    float ps = bf2f(PSh[(size_t)se * 64 + lane]);
    float pre = fmaf(wg0, di, fmaf(wg1, c2, fmaf(wg2, s2, ps + pdj)));
    if (e & 1) acc1 += silu_f(pre); else acc0 += silu_f(pre);
  }
  atomicAdd(H + (size_t)dcur * 64 + lane, acc0 + acc1);
}

// ---------------------------------------------------------------------------
// Fused node update + next-layer projection:
//   hnew[n] = h[n] + W2.H[n] + deg(n)*b2   -> hout (and kept in LDS)
//   PS/PDB(next layer) from hnew; H zeroed for next layer.
// ---------------------------------------------------------------------------
__global__ __launch_bounds__(256) void updproj_kernel(
    float* __restrict__ hout, float* __restrict__ H,
    const int* __restrict__ deg,
    const float* __restrict__ W2l, const float* __restrict__ b2l,
    const float* __restrict__ W1n, const float* __restrict__ b1n,
    ushort_t* __restrict__ PSh, ushort_t* __restrict__ PDBh, int N_) {
  __shared__ float w2sh[64 * 65];
  __shared__ float wsh[99 * 64];
  __shared__ __align__(16) float Hsh[TILE][64];
  int t = threadIdx.x;
  for (int i = t; i < 64 * 64; i += 256) w2sh[(i >> 6) * 65 + (i & 63)] = W2l[i];
  for (int i = t; i < 99 * 64; i += 256) wsh[i] = W1n[i];
  __syncthreads();
  int lane = t & 63, wib = t >> 6;
  float w2[64];
#pragma unroll
  for (int k = 0; k < 64; ++k) w2[k] = w2sh[lane * 65 + k];
  float ws_[32], wd_[32], wv_[32];
#pragma unroll
  for (int k = 0; k < 32; ++k) {
    ws_[k] = wsh[lane * 99 + k];
    wd_[k] = wsh[lane * 99 + 32 + k];
    wv_[k] = wsh[lane * 99 + 64 + k];
  }
  float bb2 = b2l[lane];
  float bb1 = b1n[lane];
  const int nTiles = (N_ + TILE - 1) / TILE;
  size_t plane = (size_t)(lane >> 5) * ((size_t)N_ * 32);
  int sn = t >> 4;   // node slot 0..15
  int sc = t & 15;   // float4 column 0..15 within 64 floats
  for (int tile = blockIdx.x; tile < nTiles; tile += gridDim.x) {
    int base = tile * TILE;
    {
      int n = base + sn;
      float4 v = (n < N_) ? *reinterpret_cast<const float4*>(H + (size_t)n * 64 + sc * 4)
                          : make_float4(0.f, 0.f, 0.f, 0.f);
      *reinterpret_cast<float4*>(&Hsh[sn][sc * 4]) = v;
    }
    __syncthreads();
#pragma unroll
    for (int q = 0; q < 4; ++q) {
      int r = wib + q * 4;
      int n = base + r;
      if (n < N_) {
        // --- out part: o = W2 . H[n] ---
        const float4* hm = reinterpret_cast<const float4*>(Hsh[r]);
        float o0 = 0.f, o1 = 0.f;
#pragma unroll
        for (int k4 = 0; k4 < 16; k4 += 2) {
          float4 m0 = hm[k4];
          float4 m1 = hm[k4 + 1];
          o0 = fmaf(m0.x, w2[k4 * 4 + 0], o0);
          o0 = fmaf(m0.y, w2[k4 * 4 + 1], o0);
          o0 = fmaf(m0.z, w2[k4 * 4 + 2], o0);
          o0 = fmaf(m0.w, w2[k4 * 4 + 3], o0);
          o1 = fmaf(m1.x, w2[k4 * 4 + 4], o1);
          o1 = fmaf(m1.y, w2[k4 * 4 + 5], o1);
          o1 = fmaf(m1.z, w2[k4 * 4 + 6], o1);
          o1 = fmaf(m1.w, w2[k4 * 4 + 7], o1);
        }
        float degf = (float)deg[n];
        size_t idx = plane + (size_t)n * 32 + (lane & 31);
        float hnew = hout[idx] + (o0 + o1) + degf * bb2;
        hout[idx] = hnew;
        // stash hnew row in LDS (own wave's row; same-wave DS ordering)
        Hsh[r][lane] = hnew;
        asm volatile("s_waitcnt lgkmcnt(0)" ::: "memory");
        // --- proj part: PS/PDB for next layer from hnew ---
        const float4* ha = reinterpret_cast<const float4*>(Hsh[r]);
        float ps0 = 0.f, ps1 = 0.f, ps2 = 0.f, ps3 = 0.f, pd0 = 0.f, pd1 = 0.f;
#pragma unroll
        for (int k4 = 0; k4 < 8; ++k4) {
          float4 a = ha[k4];
          float4 v = ha[8 + k4];
          int k = k4 * 4;
          ps0 = fmaf(a.x, ws_[k], ps0);     pd0 = fmaf(a.x, wd_[k], pd0);
          ps1 = fmaf(a.y, ws_[k + 1], ps1); pd1 = fmaf(a.y, wd_[k + 1], pd1);
          ps2 = fmaf(a.z, ws_[k + 2], ps2); pd0 = fmaf(a.z, wd_[k + 2], pd0);
          ps3 = fmaf(a.w, ws_[k + 3], ps3); pd1 = fmaf(a.w, wd_[k + 3], pd1);
          ps0 = fmaf(v.x, wv_[k], ps0);
          ps1 = fmaf(v.y, wv_[k + 1], ps1);
          ps2 = fmaf(v.z, wv_[k + 2], ps2);
          ps3 = fmaf(v.w, wv_[k + 3], ps3);
        }
        PSh[(size_t)n * 64 + lane] = f2bf((ps0 + ps1) + (ps2 + ps3));
        PDBh[(size_t)n * 64 + lane] = f2bf((pd0 + pd1) + bb1);
        H[(size_t)n * 64 + lane] = 0.0f;  // ready for next layer's edge phase
      }
    }
    __syncthreads();
  }
}

// ---------------------------------------------------------------------------
// Final node update (last layer): h[n,:] += W2 . H[n,:] + deg(n)*b2
// ---------------------------------------------------------------------------
__global__ __launch_bounds__(256) void out_kernel(
    float* __restrict__ hout, const float* __restrict__ H,
    const int* __restrict__ deg,
    const float* __restrict__ W2l, const float* __restrict__ b2l, int N_) {
  __shared__ float w2sh[64 * 65];
  __shared__ __align__(16) float Hsh[TILE][64];
  int t = threadIdx.x;
  for (int i = t; i < 64 * 64; i += 256) w2sh[(i >> 6) * 65 + (i & 63)] = W2l[i];
  __syncthreads();
  int lane = t & 63, wib = t >> 6;
  float w2[64];
#pragma unroll
  for (int k = 0; k < 64; ++k) w2[k] = w2sh[lane * 65 + k];
  float bb2 = b2l[lane];
  const int nTiles = (N_ + TILE - 1) / TILE;
  size_t plane = (size_t)(lane >> 5) * ((size_t)N_ * 32);
  int sn = t >> 4;
  int sc = t & 15;
  for (int tile = blockIdx.x; tile < nTiles; tile += gridDim.x) {
    int base = tile * TILE;
    {
      int n = base + sn;
      float4 v = (n < N_) ? *reinterpret_cast<const float4*>(H + (size_t)n * 64 + sc * 4)
                          : make_float4(0.f, 0.f, 0.f, 0.f);
      *reinterpret_cast<float4*>(&Hsh[sn][sc * 4]) = v;
    }
    __syncthreads();
#pragma unroll
    for (int q = 0; q < 4; ++q) {
      int r = wib + q * 4;
      int n = base + r;
      if (n < N_) {
        const float4* hm = reinterpret_cast<const float4*>(Hsh[r]);
        float o0 = 0.f, o1 = 0.f;
#pragma unroll
        for (int k4 = 0; k4 < 16; k4 += 2) {
          float4 m0 = hm[k4];
          float4 m1 = hm[k4 + 1];
          o0 = fmaf(m0.x, w2[k4 * 4 + 0], o0);
          o0 = fmaf(m0.y, w2[k4 * 4 + 1], o0);
          o0 = fmaf(m0.z, w2[k4 * 4 + 2], o0);
          o0 = fmaf(m0.w, w2[k4 * 4 + 3], o0);
          o1 = fmaf(m1.x, w2[k4 * 4 + 4], o1);
          o1 = fmaf(m1.y, w2[k4 * 4 + 5], o1);
          o1 = fmaf(m1.z, w2[k4 * 4 + 6], o1);
          o1 = fmaf(m1.w, w2[k4 * 4 + 7], o1);
        }
        float degf = (float)deg[n];
        size_t idx = plane + (size_t)n * 32 + (lane & 31);
        hout[idx] += (o0 + o1) + degf * bb2;
      }
    }
    __syncthreads();
  }
}

extern "C" void kernel_launch(void* const* d_in, const int* in_sizes, int n_in,
                              void* d_out, int out_size, void* d_ws, size_t ws_size,
                              hipStream_t stream) {
  const float* pos      = (const float*)d_in[0];
  const float* redshift = (const float*)d_in[1];
  const float* shapes   = (const float*)d_in[2];
  const int*   ei       = (const int*)d_in[3];
  const float* enc_s_w  = (const float*)d_in[4];
  const float* enc_s_b  = (const float*)d_in[5];
  const float* enc_v_w  = (const float*)d_in[6];
  const float* W1       = (const float*)d_in[7];
  const float* b1       = (const float*)d_in[8];
  const float* W2       = (const float*)d_in[9];
  const float* b2       = (const float*)d_in[10];

  const int N_ = in_sizes[1];      // 50000
  const int E_ = in_sizes[3] / 2;  // 1000000
  const int nchunk = (E_ + 63) / 64;
  const int padE = nchunk * 64;

  // Workspace (~46 MB): edata first (16B alignment from d_ws base)
  float4*   edata = (float4*)d_ws;                          // padE
  float*    H     = (float*)(edata + padE);                 // (N+1)*64 f32
  ushort_t* PSh   = (ushort_t*)(H + (size_t)(N_ + 1) * 64); // N*64 bf16
  ushort_t* PDBh  = PSh + (size_t)N_ * 64;                  // (N+1)*64 bf16
  int* dstS   = (int*)(PDBh + (size_t)(N_ + 1) * 64);       // padE
  int* rowptr = dstS + padE;                                // N+1
  int* deg    = rowptr + (N_ + 1);                          // N
  int* cursor = deg + N_;                                   // N (adjacent)
  int* bsum   = cursor + N_;                                // 1024

  float* hout = (float*)d_out;  // planar h lives in d_out

  encode_kernel<<<dim3((N_ * 32 + 255) / 256), dim3(256), 0, stream>>>(
      redshift, shapes, enc_s_w, enc_s_b, enc_v_w, hout, N_);

  // CSR build + layer-invariant geometry (once)
  zero_kernel<<<dim3((2 * N_ + 255) / 256), dim3(256), 0, stream>>>(deg, 2 * N_);
  deg_kernel<<<dim3((E_ + 255) / 256), dim3(256), 0, stream>>>(ei, deg, E_);
  const int nbA = (N_ + 1023) / 1024;
  scanA_kernel<<<dim3(nbA), dim3(1024), 0, stream>>>(deg, rowptr, bsum, N_);
  scanB_kernel<<<dim3(1), dim3(1024), 0, stream>>>(bsum, nbA);
  scanC_kernel<<<dim3((N_ + 255) / 256), dim3(256), 0, stream>>>(rowptr, bsum, N_);
  scatter_kernel<<<dim3((padE + 255) / 256), dim3(256), 0, stream>>>(
      ei, pos, rowptr, cursor, edata, dstS, E_, padE, N_);

  const int edgeBlocks = (nchunk + WPB - 1) / WPB;

  // layer 0 projections
  psd_kernel<<<dim3(1024), dim3(256), 0, stream>>>(
      hout, W1, b1, PSh, PDBh, H, N_);

  for (int l = 0; l < 3; ++l) {
    const float* W2l = W2 + (size_t)l * 64 * 64;
    const float* b2l = b2 + (size_t)l * 64;
    edge_kernel<<<dim3(edgeBlocks), dim3(256), 0, stream>>>(
        PSh, PDBh, edata, dstS, W1 + (size_t)l * 64 * 99, H, nchunk);
    if (l < 2) {
      updproj_kernel<<<dim3(1024), dim3(256), 0, stream>>>(
          hout, H, deg, W2l, b2l,
          W1 + (size_t)(l + 1) * 64 * 99, b1 + (size_t)(l + 1) * 64,
          PSh, PDBh, N_);
    } else {
      out_kernel<<<dim3(1024), dim3(256), 0, stream>>>(
          hout, H, deg, W2l, b2l, N_);
    }
  }
}

// Round 8
// 324.721 us; speedup vs baseline: 7.1192x; 1.2369x over previous
//
#include <hip/hip_runtime.h>
#include <hip/hip_bf16.h>

#define WPB 4   // waves per block (256 threads)
#define TILE 16 // node rows staged per block iteration

typedef unsigned short ushort_t;
typedef unsigned int uint_t;

__device__ __forceinline__ float silu_f(float x) {
  return x * __builtin_amdgcn_rcpf(1.0f + __expf(-x));
}
__device__ __forceinline__ int rfl(int x) { return __builtin_amdgcn_readfirstlane(x); }
__device__ __forceinline__ float readlane_f(float v, int l) {
  return __int_as_float(__builtin_amdgcn_readlane(__float_as_int(v), l));
}
// f32 -> bf16 round-to-nearest-even
__device__ __forceinline__ ushort_t f2bf(float f) {
  uint_t u = __float_as_uint(f);
  u += 0x7FFFu + ((u >> 16) & 1u);
  return (ushort_t)(u >> 16);
}
__device__ __forceinline__ float bf2f(ushort_t b) {
  return __uint_as_float(((uint_t)b) << 16);
}

// ---------------------------------------------------------------------------
// Encode directly into d_out (planar): out[0..N*32) = h_s, out[N*32..) = h_v
// ---------------------------------------------------------------------------
__global__ void encode_kernel(const float* __restrict__ redshift,
                              const float* __restrict__ shapes,
                              const float* __restrict__ enc_s_w,
                              const float* __restrict__ enc_s_b,
                              const float* __restrict__ enc_v_w,
                              float* __restrict__ hout, int N_) {
  int tid = blockIdx.x * blockDim.x + threadIdx.x;
  int n = tid >> 5;
  int j = tid & 31;
  if (n >= N_) return;
  float r = redshift[n];
  float hs = fmaxf(fmaf(r, enc_s_w[j], enc_s_b[j]), 0.0f);
  float x0 = shapes[n * 2 + 0];
  float x1 = shapes[n * 2 + 1];
  float hv = fmaf(x0, enc_v_w[j * 2 + 0], x1 * enc_v_w[j * 2 + 1]);
  hout[(size_t)n * 32 + j] = hs;
  hout[(size_t)N_ * 32 + (size_t)n * 32 + j] = hv;
}

__global__ void zero_kernel(int* __restrict__ p, int n) {
  int i = blockIdx.x * blockDim.x + threadIdx.x;
  if (i < n) p[i] = 0;
}

// ---------------------------------------------------------------------------
// CSR build (once): degree, hierarchical scan, ONE fused scatter pass.
// ---------------------------------------------------------------------------
__global__ void deg_kernel(const int* __restrict__ ei, int* __restrict__ deg, int E_) {
  int e = blockIdx.x * blockDim.x + threadIdx.x;
  if (e < E_) atomicAdd(&deg[ei[E_ + e]], 1);
}

__global__ __launch_bounds__(1024) void scanA_kernel(const int* __restrict__ deg,
                                                     int* __restrict__ rowptr,
                                                     int* __restrict__ bsum, int n) {
  __shared__ int wsum[16];
  int t = threadIdx.x, lane = t & 63, wid = t >> 6;
  int i = blockIdx.x * 1024 + t;
  int v = (i < n) ? deg[i] : 0;
  int x = v;
#pragma unroll
  for (int off = 1; off < 64; off <<= 1) {
    int y = __shfl_up(x, off);
    if (lane >= off) x += y;
  }
  if (lane == 63) wsum[wid] = x;
  __syncthreads();
  if (t == 0) {
    int run = 0;
#pragma unroll
    for (int w = 0; w < 16; ++w) { int s = wsum[w]; wsum[w] = run; run += s; }
  }
  __syncthreads();
  int inc = x + wsum[wid];
  if (i < n) rowptr[i + 1] = inc;  // inclusive within block
  if (t == 1023) bsum[blockIdx.x] = inc;
}

__global__ __launch_bounds__(1024) void scanB_kernel(int* __restrict__ bsum, int nb) {
  __shared__ int wsum[16];
  int t = threadIdx.x, lane = t & 63, wid = t >> 6;
  int v = (t < nb) ? bsum[t] : 0;
  int x = v;
#pragma unroll
  for (int off = 1; off < 64; off <<= 1) {
    int y = __shfl_up(x, off);
    if (lane >= off) x += y;
  }
  if (lane == 63) wsum[wid] = x;
  __syncthreads();
  if (t == 0) {
    int run = 0;
#pragma unroll
    for (int w = 0; w < 16; ++w) { int s = wsum[w]; wsum[w] = run; run += s; }
  }
  __syncthreads();
  if (t < nb) bsum[t] = x - v + wsum[wid];  // exclusive
}

__global__ void scanC_kernel(int* __restrict__ rowptr, const int* __restrict__ bsum, int n) {
  int i = blockIdx.x * blockDim.x + threadIdx.x;
  if (i == 0) rowptr[0] = 0;
  if (i < n) rowptr[i + 1] += bsum[i >> 10];
}

// Fused scatter, ONE 16B record per edge:
//   edata = (dist f32, [s2|c2] bf16x2, src bits, dst bits)
__global__ void scatter_kernel(const int* __restrict__ ei, const float* __restrict__ pos,
                               const int* __restrict__ rowptr, int* __restrict__ cursor,
                               float4* __restrict__ edata,
                               int E_, int padE, int N_) {
  int e = blockIdx.x * blockDim.x + threadIdx.x;
  if (e >= padE) return;
  if (e >= E_) {  // sentinel slots -> pad row N_ of H/PDB
    edata[e] = make_float4(0.f, 0.f, __int_as_float(0), __int_as_float(N_));
    return;
  }
  int s = ei[e];
  int d = ei[E_ + e];
  int idx = rowptr[d] + atomicAdd(&cursor[d], 1);
  float dx = pos[s * 2 + 0] - pos[d * 2 + 0];
  float dy = pos[s * 2 + 1] - pos[d * 2 + 1];
  float r2 = fmaf(dx, dx, dy * dy);
  float dist = sqrtf(r2) + 1e-6f;
  float c2 = 1.0f, s2 = 0.0f;
  if (r2 > 0.0f) {
    float inv = 1.0f / r2;
    c2 = (dx * dx - dy * dy) * inv;
    s2 = 2.0f * dx * dy * inv;
  }
  uint_t pk = ((uint_t)f2bf(s2) << 16) | (uint_t)f2bf(c2);
  edata[idx] = make_float4(dist, __uint_as_float(pk),
                           __int_as_float(s), __int_as_float(d));
}

// ---------------------------------------------------------------------------
// Standalone projections (layer 0 only) + H zeroing.
//   PS[n,j]  = h_s[n]·W1[j,0:32] + h_v[n]·W1[j,64:96]   (bf16)
//   PDB[n,j] = h_s[n]·W1[j,32:64] + b1[j]               (bf16)
// ---------------------------------------------------------------------------
__global__ __launch_bounds__(256) void psd_kernel(
    const float* __restrict__ hout, const float* __restrict__ W1l,
    const float* __restrict__ b1l,
    ushort_t* __restrict__ PSh, ushort_t* __restrict__ PDBh,
    float* __restrict__ H, int N_) {
  __shared__ float wsh[99 * 64];
  __shared__ __align__(16) float hsh[TILE][64];
  int t = threadIdx.x;
  for (int i = t; i < 99 * 64; i += 256) wsh[i] = W1l[i];
  __syncthreads();
  int lane = t & 63, wib = t >> 6;
  float ws_[32], wd_[32], wv_[32];
#pragma unroll
  for (int k = 0; k < 32; ++k) {
    ws_[k] = wsh[lane * 99 + k];
    wd_[k] = wsh[lane * 99 + 32 + k];
    wv_[k] = wsh[lane * 99 + 64 + k];
  }
  float bb1 = b1l[lane];
  const int nTiles = (N_ + TILE - 1) / TILE;
  const float* hvbase = hout + (size_t)N_ * 32;
  int tt = t & 127;
  int sn = tt >> 3;        // node slot 0..15
  int sc = tt & 7;         // float4 column 0..7 within 32 floats
  for (int tile = blockIdx.x; tile < nTiles; tile += gridDim.x) {
    int base = tile * TILE;
    {
      int n = base + sn;
      const float* src = (t < 128) ? (hout + (size_t)n * 32 + sc * 4)
                                   : (hvbase + (size_t)n * 32 + sc * 4);
      float4 v = (n < N_) ? *reinterpret_cast<const float4*>(src)
                          : make_float4(0.f, 0.f, 0.f, 0.f);
      *reinterpret_cast<float4*>(&hsh[sn][(t < 128 ? 0 : 32) + sc * 4]) = v;
    }
    __syncthreads();
#pragma unroll
    for (int q = 0; q < 4; ++q) {
      int r = wib + q * 4;
      int n = base + r;
      if (n < N_) {
        const float4* ha = reinterpret_cast<const float4*>(hsh[r]);
        float ps0 = 0.f, ps1 = 0.f, ps2 = 0.f, ps3 = 0.f, pd0 = 0.f, pd1 = 0.f;
#pragma unroll
        for (int k4 = 0; k4 < 8; ++k4) {
          float4 a = ha[k4];
          float4 v = ha[8 + k4];
          int k = k4 * 4;
          ps0 = fmaf(a.x, ws_[k], ps0);     pd0 = fmaf(a.x, wd_[k], pd0);
          ps1 = fmaf(a.y, ws_[k + 1], ps1); pd1 = fmaf(a.y, wd_[k + 1], pd1);
          ps2 = fmaf(a.z, ws_[k + 2], ps2); pd0 = fmaf(a.z, wd_[k + 2], pd0);
          ps3 = fmaf(a.w, ws_[k + 3], ps3); pd1 = fmaf(a.w, wd_[k + 3], pd1);
          ps0 = fmaf(v.x, wv_[k], ps0);
          ps1 = fmaf(v.y, wv_[k + 1], ps1);
          ps2 = fmaf(v.z, wv_[k + 2], ps2);
          ps3 = fmaf(v.w, wv_[k + 3], ps3);
        }
        PSh[(size_t)n * 64 + lane] = f2bf((ps0 + ps1) + (ps2 + ps3));
        PDBh[(size_t)n * 64 + lane] = f2bf((pd0 + pd1) + bb1);
        H[(size_t)n * 64 + lane] = 0.0f;
      }
    }
    __syncthreads();
  }
}

// ---------------------------------------------------------------------------
// Edge phase: one wave per 64-edge chunk of the dst-sorted edge array.
// PS gathers batched 8-deep into named registers (forces 8 loads in flight;
// round-7's compiler register-minimization capped ILP at ~4). Segment-
// boundary PDB values prefetched a full segment ahead. Dual accumulators.
// ---------------------------------------------------------------------------
__global__ __launch_bounds__(256) void edge_kernel(
    const ushort_t* __restrict__ PSh, const ushort_t* __restrict__ PDBh,
    const float4* __restrict__ edata,
    const float* __restrict__ W1l, float* __restrict__ H, int nchunk) {
  int lane = threadIdx.x & 63, wib = threadIdx.x >> 6;
  int chunk = blockIdx.x * WPB + wib;
  if (chunk >= nchunk) return;
  int base = chunk << 6;
  float wg0 = W1l[lane * 99 + 96];
  float wg1 = W1l[lane * 99 + 97];
  float wg2 = W1l[lane * 99 + 98];
  float4 ed = edata[base + lane];  // x=dist, y=[s2|c2]bf16, z=src, w=dst
  int sv = __float_as_int(ed.z);
  int dv = __float_as_int(ed.w);
  int dprev = __shfl_up(dv, 1);
  unsigned long long bmask = __ballot(dv != dprev) & ~1ull;
  int dcur = rfl(dv);
  float pdj = bf2f(PDBh[(size_t)dcur * 64 + lane]);
  int bnext = bmask ? (int)__builtin_ctzll(bmask) : 64;
  int dnext = (bnext < 64) ? __builtin_amdgcn_readlane(dv, bnext) : dcur;
  float pdj_next = bf2f(PDBh[(size_t)dnext * 64 + lane]);
  float acc0 = 0.0f, acc1 = 0.0f;
#pragma unroll
  for (int g = 0; g < 8; ++g) {
    // --- batch-issue 8 PS gathers (independent; stay in flight together) ---
    float ps0, ps1, ps2, ps3, ps4, ps5, ps6, ps7;
    {
      int s0 = __builtin_amdgcn_readlane(sv, g * 8 + 0);
      int s1 = __builtin_amdgcn_readlane(sv, g * 8 + 1);
      int s2_ = __builtin_amdgcn_readlane(sv, g * 8 + 2);
      int s3 = __builtin_amdgcn_readlane(sv, g * 8 + 3);
      int s4 = __builtin_amdgcn_readlane(sv, g * 8 + 4);
      int s5 = __builtin_amdgcn_readlane(sv, g * 8 + 5);
      int s6 = __builtin_amdgcn_readlane(sv, g * 8 + 6);
      int s7 = __builtin_amdgcn_readlane(sv, g * 8 + 7);
      ps0 = bf2f(PSh[(size_t)s0 * 64 + lane]);
      ps1 = bf2f(PSh[(size_t)s1 * 64 + lane]);
      ps2 = bf2f(PSh[(size_t)s2_ * 64 + lane]);
      ps3 = bf2f(PSh[(size_t)s3 * 64 + lane]);
      ps4 = bf2f(PSh[(size_t)s4 * 64 + lane]);
      ps5 = bf2f(PSh[(size_t)s5 * 64 + lane]);
      ps6 = bf2f(PSh[(size_t)s6 * 64 + lane]);
      ps7 = bf2f(PSh[(size_t)s7 * 64 + lane]);
    }
#pragma unroll
    for (int i = 0; i < 8; ++i) {
      int e = g * 8 + i;
      if (e == bnext) {  // wave-uniform scalar compare
        atomicAdd(H + (size_t)dcur * 64 + lane, acc0 + acc1);
        acc0 = acc1 = 0.0f;
        dcur = dnext;
        pdj = pdj_next;  // prefetched a whole segment ago
        bmask &= bmask - 1;
        bnext = bmask ? (int)__builtin_ctzll(bmask) : 64;
        dnext = (bnext < 64) ? __builtin_amdgcn_readlane(dv, bnext) : dcur;
        pdj_next = bf2f(PDBh[(size_t)dnext * 64 + lane]);
      }
      float psv = (i == 0) ? ps0 : (i == 1) ? ps1 : (i == 2) ? ps2 :
                  (i == 3) ? ps3 : (i == 4) ? ps4 : (i == 5) ? ps5 :
                  (i == 6) ? ps6 : ps7;
      float di = readlane_f(ed.x, e);
      uint_t pk = (uint_t)__builtin_amdgcn_readlane(__float_as_int(ed.y), e);
      float c2 = __uint_as_float(pk << 16);
      float s2 = __uint_as_float(pk & 0xFFFF0000u);
      float pre = fmaf(wg0, di, fmaf(wg1, c2, fmaf(wg2, s2, psv + pdj)));
      if (e & 1) acc1 += silu_f(pre); else acc0 += silu_f(pre);
    }
  }
  atomicAdd(H + (size_t)dcur * 64 + lane, acc0 + acc1);
}

// ---------------------------------------------------------------------------
// Fused node update + next-layer projection:
//   hnew[n] = h[n] + W2.H[n] + deg(n)*b2   -> hout (and kept in LDS)
//   PS/PDB(next layer) from hnew; H zeroed for next layer.
// ---------------------------------------------------------------------------
__global__ __launch_bounds__(256) void updproj_kernel(
    float* __restrict__ hout, float* __restrict__ H,
    const int* __restrict__ deg,
    const float* __restrict__ W2l, const float* __restrict__ b2l,
    const float* __restrict__ W1n, const float* __restrict__ b1n,
    ushort_t* __restrict__ PSh, ushort_t* __restrict__ PDBh, int N_) {
  __shared__ float w2sh[64 * 65];
  __shared__ float wsh[99 * 64];
  __shared__ __align__(16) float Hsh[TILE][64];
  int t = threadIdx.x;
  for (int i = t; i < 64 * 64; i += 256) w2sh[(i >> 6) * 65 + (i & 63)] = W2l[i];
  for (int i = t; i < 99 * 64; i += 256) wsh[i] = W1n[i];
  __syncthreads();
  int lane = t & 63, wib = t >> 6;
  float w2[64];
#pragma unroll
  for (int k = 0; k < 64; ++k) w2[k] = w2sh[lane * 65 + k];
  float ws_[32], wd_[32], wv_[32];
#pragma unroll
  for (int k = 0; k < 32; ++k) {
    ws_[k] = wsh[lane * 99 + k];
    wd_[k] = wsh[lane * 99 + 32 + k];
    wv_[k] = wsh[lane * 99 + 64 + k];
  }
  float bb2 = b2l[lane];
  float bb1 = b1n[lane];
  const int nTiles = (N_ + TILE - 1) / TILE;
  size_t plane = (size_t)(lane >> 5) * ((size_t)N_ * 32);
  int sn = t >> 4;   // node slot 0..15
  int sc = t & 15;   // float4 column 0..15 within 64 floats
  for (int tile = blockIdx.x; tile < nTiles; tile += gridDim.x) {
    int base = tile * TILE;
    {
      int n = base + sn;
      float4 v = (n < N_) ? *reinterpret_cast<const float4*>(H + (size_t)n * 64 + sc * 4)
                          : make_float4(0.f, 0.f, 0.f, 0.f);
      *reinterpret_cast<float4*>(&Hsh[sn][sc * 4]) = v;
    }
    __syncthreads();
#pragma unroll
    for (int q = 0; q < 4; ++q) {
      int r = wib + q * 4;
      int n = base + r;
      if (n < N_) {
        // --- out part: o = W2 . H[n] ---
        const float4* hm = reinterpret_cast<const float4*>(Hsh[r]);
        float o0 = 0.f, o1 = 0.f;
#pragma unroll
        for (int k4 = 0; k4 < 16; k4 += 2) {
          float4 m0 = hm[k4];
          float4 m1 = hm[k4 + 1];
          o0 = fmaf(m0.x, w2[k4 * 4 + 0], o0);
          o0 = fmaf(m0.y, w2[k4 * 4 + 1], o0);
          o0 = fmaf(m0.z, w2[k4 * 4 + 2], o0);
          o0 = fmaf(m0.w, w2[k4 * 4 + 3], o0);
          o1 = fmaf(m1.x, w2[k4 * 4 + 4], o1);
          o1 = fmaf(m1.y, w2[k4 * 4 + 5], o1);
          o1 = fmaf(m1.z, w2[k4 * 4 + 6], o1);
          o1 = fmaf(m1.w, w2[k4 * 4 + 7], o1);
        }
        float degf = (float)deg[n];
        size_t idx = plane + (size_t)n * 32 + (lane & 31);
        float hnew = hout[idx] + (o0 + o1) + degf * bb2;
        hout[idx] = hnew;
        // stash hnew row in LDS (own wave's row; same-wave DS ordering)
        Hsh[r][lane] = hnew;
        asm volatile("s_waitcnt lgkmcnt(0)" ::: "memory");
        // --- proj part: PS/PDB for next layer from hnew ---
        const float4* ha = reinterpret_cast<const float4*>(Hsh[r]);
        float ps0 = 0.f, ps1 = 0.f, ps2 = 0.f, ps3 = 0.f, pd0 = 0.f, pd1 = 0.f;
#pragma unroll
        for (int k4 = 0; k4 < 8; ++k4) {
          float4 a = ha[k4];
          float4 v = ha[8 + k4];
          int k = k4 * 4;
          ps0 = fmaf(a.x, ws_[k], ps0);     pd0 = fmaf(a.x, wd_[k], pd0);
          ps1 = fmaf(a.y, ws_[k + 1], ps1); pd1 = fmaf(a.y, wd_[k + 1], pd1);
          ps2 = fmaf(a.z, ws_[k + 2], ps2); pd0 = fmaf(a.z, wd_[k + 2], pd0);
          ps3 = fmaf(a.w, ws_[k + 3], ps3); pd1 = fmaf(a.w, wd_[k + 3], pd1);
          ps0 = fmaf(v.x, wv_[k], ps0);
          ps1 = fmaf(v.y, wv_[k + 1], ps1);
          ps2 = fmaf(v.z, wv_[k + 2], ps2);
          ps3 = fmaf(v.w, wv_[k + 3], ps3);
        }
        PSh[(size_t)n * 64 + lane] = f2bf((ps0 + ps1) + (ps2 + ps3));
        PDBh[(size_t)n * 64 + lane] = f2bf((pd0 + pd1) + bb1);
        H[(size_t)n * 64 + lane] = 0.0f;  // ready for next layer's edge phase
      }
    }
    __syncthreads();
  }
}

// ---------------------------------------------------------------------------
// Final node update (last layer): h[n,:] += W2 . H[n,:] + deg(n)*b2
// ---------------------------------------------------------------------------
__global__ __launch_bounds__(256) void out_kernel(
    float* __restrict__ hout, const float* __restrict__ H,
    const int* __restrict__ deg,
    const float* __restrict__ W2l, const float* __restrict__ b2l, int N_) {
  __shared__ float w2sh[64 * 65];
  __shared__ __align__(16) float Hsh[TILE][64];
  int t = threadIdx.x;
  for (int i = t; i < 64 * 64; i += 256) w2sh[(i >> 6) * 65 + (i & 63)] = W2l[i];
  __syncthreads();
  int lane = t & 63, wib = t >> 6;
  float w2[64];
#pragma unroll
  for (int k = 0; k < 64; ++k) w2[k] = w2sh[lane * 65 + k];
  float bb2 = b2l[lane];
  const int nTiles = (N_ + TILE - 1) / TILE;
  size_t plane = (size_t)(lane >> 5) * ((size_t)N_ * 32);
  int sn = t >> 4;
  int sc = t & 15;
  for (int tile = blockIdx.x; tile < nTiles; tile += gridDim.x) {
    int base = tile * TILE;
    {
      int n = base + sn;
      float4 v = (n < N_) ? *reinterpret_cast<const float4*>(H + (size_t)n * 64 + sc * 4)
                          : make_float4(0.f, 0.f, 0.f, 0.f);
      *reinterpret_cast<float4*>(&Hsh[sn][sc * 4]) = v;
    }
    __syncthreads();
#pragma unroll
    for (int q = 0; q < 4; ++q) {
      int r = wib + q * 4;
      int n = base + r;
      if (n < N_) {
        const float4* hm = reinterpret_cast<const float4*>(Hsh[r]);
        float o0 = 0.f, o1 = 0.f;
#pragma unroll
        for (int k4 = 0; k4 < 16; k4 += 2) {
          float4 m0 = hm[k4];
          float4 m1 = hm[k4 + 1];
          o0 = fmaf(m0.x, w2[k4 * 4 + 0], o0);
          o0 = fmaf(m0.y, w2[k4 * 4 + 1], o0);
          o0 = fmaf(m0.z, w2[k4 * 4 + 2], o0);
          o0 = fmaf(m0.w, w2[k4 * 4 + 3], o0);
          o1 = fmaf(m1.x, w2[k4 * 4 + 4], o1);
          o1 = fmaf(m1.y, w2[k4 * 4 + 5], o1);
          o1 = fmaf(m1.z, w2[k4 * 4 + 6], o1);
          o1 = fmaf(m1.w, w2[k4 * 4 + 7], o1);
        }
        float degf = (float)deg[n];
        size_t idx = plane + (size_t)n * 32 + (lane & 31);
        hout[idx] += (o0 + o1) + degf * bb2;
      }
    }
    __syncthreads();
  }
}

extern "C" void kernel_launch(void* const* d_in, const int* in_sizes, int n_in,
                              void* d_out, int out_size, void* d_ws, size_t ws_size,
                              hipStream_t stream) {
  const float* pos      = (const float*)d_in[0];
  const float* redshift = (const float*)d_in[1];
  const float* shapes   = (const float*)d_in[2];
  const int*   ei       = (const int*)d_in[3];
  const float* enc_s_w  = (const float*)d_in[4];
  const float* enc_s_b  = (const float*)d_in[5];
  const float* enc_v_w  = (const float*)d_in[6];
  const float* W1       = (const float*)d_in[7];
  const float* b1       = (const float*)d_in[8];
  const float* W2       = (const float*)d_in[9];
  const float* b2       = (const float*)d_in[10];

  const int N_ = in_sizes[1];      // 50000
  const int E_ = in_sizes[3] / 2;  // 1000000
  const int nchunk = (E_ + 63) / 64;
  const int padE = nchunk * 64;

  // Workspace (~42 MB): edata first (16B alignment from d_ws base)
  float4*   edata = (float4*)d_ws;                          // padE
  float*    H     = (float*)(edata + padE);                 // (N+1)*64 f32
  ushort_t* PSh   = (ushort_t*)(H + (size_t)(N_ + 1) * 64); // N*64 bf16
  ushort_t* PDBh  = PSh + (size_t)N_ * 64;                  // (N+1)*64 bf16
  int* rowptr = (int*)(PDBh + (size_t)(N_ + 1) * 64);       // N+1
  int* deg    = rowptr + (N_ + 1);                          // N
  int* cursor = deg + N_;                                   // N (adjacent)
  int* bsum   = cursor + N_;                                // 1024

  float* hout = (float*)d_out;  // planar h lives in d_out

  encode_kernel<<<dim3((N_ * 32 + 255) / 256), dim3(256), 0, stream>>>(
      redshift, shapes, enc_s_w, enc_s_b, enc_v_w, hout, N_);

  // CSR build + layer-invariant geometry (once)
  zero_kernel<<<dim3((2 * N_ + 255) / 256), dim3(256), 0, stream>>>(deg, 2 * N_);
  deg_kernel<<<dim3((E_ + 255) / 256), dim3(256), 0, stream>>>(ei, deg, E_);
  const int nbA = (N_ + 1023) / 1024;
  scanA_kernel<<<dim3(nbA), dim3(1024), 0, stream>>>(deg, rowptr, bsum, N_);
  scanB_kernel<<<dim3(1), dim3(1024), 0, stream>>>(bsum, nbA);
  scanC_kernel<<<dim3((N_ + 255) / 256), dim3(256), 0, stream>>>(rowptr, bsum, N_);
  scatter_kernel<<<dim3((padE + 255) / 256), dim3(256), 0, stream>>>(
      ei, pos, rowptr, cursor, edata, E_, padE, N_);

  const int edgeBlocks = (nchunk + WPB - 1) / WPB;

  // layer 0 projections
  psd_kernel<<<dim3(1024), dim3(256), 0, stream>>>(
      hout, W1, b1, PSh, PDBh, H, N_);

  for (int l = 0; l < 3; ++l) {
    const float* W2l = W2 + (size_t)l * 64 * 64;
    const float* b2l = b2 + (size_t)l * 64;
    edge_kernel<<<dim3(edgeBlocks), dim3(256), 0, stream>>>(
        PSh, PDBh, edata, W1 + (size_t)l * 64 * 99, H, nchunk);
    if (l < 2) {
      updproj_kernel<<<dim3(1024), dim3(256), 0, stream>>>(
          hout, H, deg, W2l, b2l,
          W1 + (size_t)(l + 1) * 64 * 99, b1 + (size_t)(l + 1) * 64,
          PSh, PDBh, N_);
    } else {
      out_kernel<<<dim3(1024), dim3(256), 0, stream>>>(
          hout, H, deg, W2l, b2l, N_);
    }
  }
}